// Round 3
// baseline (75542.273 us; speedup 1.0000x reference)
//
#include <hip/hip_runtime.h>
#include <math.h>

typedef unsigned int u32;

#define T_    600
#define FIN_  120

// ---- ws byte offsets ----
#define OFF_BAR      0ull          // 2048 B barrier counters
#define OFF_HENC     2048ull       // [2 parity][2 dir][512][32] f32 = 262144
#define OFF_CENC     264192ull     // [2 dir][512][32] = 131072 (fallback path only)
#define OFF_HD       395264ull     // [2 parity][32][512] = 131072
#define OFF_CD       526336ull     // [32][512] = 65536
#define STATE_BYTES  591872ull     // memset-0 region
#define OFF_LAST     591872ull     // [32][512]
#define OFF_Q        657408ull     // [32][512]
#define OFF_CTX      722944ull     // [32][1024]
#define OFF_SCORES   854016ull     // [32][600]
#define OFF_STATS    930816ull     // [32][2]
#define OFF_AUDIOT   931840ull     // [600][120][32] = 9216000
#define OFF_ENC2     10147840ull   // [32][1024][600] = 78643200
#define OFF_KEYT     88791040ull   // [32][512][600] = 39321600
#define OFF_VAL      128112640ull  // [32][600][1024] = 78643200

__device__ __forceinline__ float sigf(float x) { return 1.0f / (1.0f + expf(-x)); }

// ---------------- prep ----------------
__global__ __launch_bounds__(256) void k_prep_audio(const float* __restrict__ audio,
                                                    float* __restrict__ audio_T) {
  int idx = blockIdx.x * 256 + threadIdx.x;
  if (idx >= T_ * FIN_ * 32) return;
  int b = idx & 31;
  int r = idx >> 5;
  int f = r % FIN_;
  int t = r / FIN_;
  audio_T[idx] = audio[(size_t)b * (T_ * FIN_) + t * FIN_ + f];
}

__global__ __launch_bounds__(256) void k_init_last(const float* __restrict__ E,
                                                   float* __restrict__ last) {
  int idx = blockIdx.x * 256 + threadIdx.x;
  if (idx < 32 * 512) last[idx] = E[idx & 511];
}

// ---------------- shared structs ----------------
struct EncP {
  const float* audio_T;
  const float* Wih_f; const float* Whh_f; const float* b_f;
  const float* Wih_b; const float* Whh_b; const float* b_b;
  float* h_enc; float* c_enc; float* enc2;
  u32* bar;
};

// ---------------- persistent cooperative encoder (256 blocks x 256) ----------------
// 4 groups (dir x bhalf) x 64 blocks. Each block: 8 j-rows. c in registers.
// Whh/Wih streamed from L2 (per-block slice = 64KB, disjoint). h via LDS.
__global__ __launch_bounds__(256) void k_encoder(EncP P) {
  __shared__ float hl[8192];          // [512 j][16 b]
  const int tid = threadIdx.x, bid = blockIdx.x;
  const int grp = bid >> 6;           // 0..3 : dir*2+bhalf
  const int dir = grp >> 1, bhalf = grp & 1;
  const int jblk = bid & 63;
  const int b_lo = tid & 15;
  const int half = (tid >> 4) & 1;
  const int j_lo = tid >> 5;          // 0..7
  const int j = jblk * 8 + j_lo;
  const int bG = bhalf * 16 + b_lo;
  const float* Wih  = dir ? P.Wih_b : P.Wih_f;
  const float* Whh  = dir ? P.Whh_b : P.Whh_f;
  const float* bias = dir ? P.b_b   : P.b_f;
  u32* ctr = P.bar + grp * 64;

  const float* WihR0 = Wih + (size_t)(j       ) * 120 + half * 60;
  const float* WihR1 = Wih + (size_t)(512  + j) * 120 + half * 60;
  const float* WihR2 = Wih + (size_t)(1024 + j) * 120 + half * 60;
  const float* WihR3 = Wih + (size_t)(1536 + j) * 120 + half * 60;
  const float* WhhR0 = Whh + (size_t)(j       ) * 512 + half * 256;
  const float* WhhR1 = Whh + (size_t)(512  + j) * 512 + half * 256;
  const float* WhhR2 = Whh + (size_t)(1024 + j) * 512 + half * 256;
  const float* WhhR3 = Whh + (size_t)(1536 + j) * 512 + half * 256;
  const float bia0 = bias[j], bia1 = bias[512 + j], bia2 = bias[1024 + j], bia3 = bias[1536 + j];

  float creg = 0.f;   // cell state for (bG, j), owned by half==0 threads

  for (int s = 0; s < 600; s++) {
    const int t = dir ? (599 - s) : s;
    const int p = s & 1;
    // stage h[p] (this group's 16 batch columns) into LDS
    {
      const float* hsrc = P.h_enc + (size_t)(p * 2 + dir) * 16384 + bhalf * 16;
      for (int idx = tid; idx < 8192; idx += 256) {
        int jj = idx >> 4, bb = idx & 15;
        hl[jj * 16 + bb] = hsrc[jj * 32 + bb];
      }
    }
    __syncthreads();

    float a0 = 0.f, a1 = 0.f, a2 = 0.f, a3 = 0.f;
    // x part: 60 k per half
    {
      const float* xg = P.audio_T + (size_t)t * 3840 + half * 1920 + bG;
      for (int kl = 0; kl < 60; kl += 4) {
        float4 w0 = *(const float4*)(WihR0 + kl);
        float4 w1 = *(const float4*)(WihR1 + kl);
        float4 w2 = *(const float4*)(WihR2 + kl);
        float4 w3 = *(const float4*)(WihR3 + kl);
        float x0 = xg[(kl + 0) * 32], x1 = xg[(kl + 1) * 32];
        float x2 = xg[(kl + 2) * 32], x3 = xg[(kl + 3) * 32];
        a0 += w0.x * x0 + w0.y * x1 + w0.z * x2 + w0.w * x3;
        a1 += w1.x * x0 + w1.y * x1 + w1.z * x2 + w1.w * x3;
        a2 += w2.x * x0 + w2.y * x1 + w2.z * x2 + w2.w * x3;
        a3 += w3.x * x0 + w3.y * x1 + w3.z * x2 + w3.w * x3;
      }
    }
    // h part: 256 k per half
    {
      const float* hb = hl + half * 4096 + b_lo;
      #pragma unroll 4
      for (int kl = 0; kl < 256; kl += 4) {
        float4 w0 = *(const float4*)(WhhR0 + kl);
        float4 w1 = *(const float4*)(WhhR1 + kl);
        float4 w2 = *(const float4*)(WhhR2 + kl);
        float4 w3 = *(const float4*)(WhhR3 + kl);
        float x0 = hb[(kl + 0) * 16], x1 = hb[(kl + 1) * 16];
        float x2 = hb[(kl + 2) * 16], x3 = hb[(kl + 3) * 16];
        a0 += w0.x * x0 + w0.y * x1 + w0.z * x2 + w0.w * x3;
        a1 += w1.x * x0 + w1.y * x1 + w1.z * x2 + w1.w * x3;
        a2 += w2.x * x0 + w2.y * x1 + w2.z * x2 + w2.w * x3;
        a3 += w3.x * x0 + w3.y * x1 + w3.z * x2 + w3.w * x3;
      }
    }
    a0 += __shfl_xor(a0, 16);
    a1 += __shfl_xor(a1, 16);
    a2 += __shfl_xor(a2, 16);
    a3 += __shfl_xor(a3, 16);
    if (half == 0) {
      float gi = a0 + bia0, gf = a1 + bia1, gg = a2 + bia2, go = a3 + bia3;
      creg = sigf(gf) * creg + sigf(gi) * tanhf(gg);
      float hn = sigf(go) * tanhf(creg);
      P.h_enc[(size_t)((p ^ 1) * 2 + dir) * 16384 + j * 32 + bG] = hn;
      P.enc2[(size_t)bG * 614400 + (size_t)(dir * 512 + j) * 600 + t] = hn;
    }
    // group barrier (64 blocks)
    __syncthreads();
    if (tid == 0) {
      __threadfence();
      __hip_atomic_fetch_add(ctr, 1u, __ATOMIC_ACQ_REL, __HIP_MEMORY_SCOPE_AGENT);
      u32 tgt = (u32)(s + 1) * 64u;
      while (__hip_atomic_load(ctr, __ATOMIC_ACQUIRE, __HIP_MEMORY_SCOPE_AGENT) < tgt)
        __builtin_amdgcn_s_sleep(2);
      __threadfence();
    }
    __syncthreads();
  }
}

// ---------------- fallback encoder: one step per launch (512 blocks, r2-proven) ----------------
__global__ __launch_bounds__(256) void k_enc_step(EncP P, int s) {
  __shared__ float Wl[8192];
  __shared__ float hl[8192];
  const int tid = threadIdx.x, bid = blockIdx.x;
  const int grp = bid >> 7;
  const int dir = grp >> 1, bhalf = grp & 1;
  const int jblk = bid & 127;
  const int b_lo = tid & 15, quad = (tid >> 4) & 3, j_lo = tid >> 6;
  const int j = jblk * 4 + j_lo;
  const int bG = bhalf * 16 + b_lo;
  const float* Wih  = dir ? P.Wih_b : P.Wih_f;
  const float* Whh  = dir ? P.Whh_b : P.Whh_f;
  const float* bias = dir ? P.b_b   : P.b_f;
  const int t = dir ? (599 - s) : s;
  const int p = s & 1;
  for (int rr = 0; rr < 16; rr++) {
    int R = ((rr & 3) << 9) + jblk * 4 + (rr >> 2);
    for (int c = tid; c < 512; c += 256) Wl[rr * 512 + c] = Whh[(size_t)R * 512 + c];
  }
  {
    const float* hsrc = P.h_enc + (size_t)(p * 2 + dir) * 16384;
    for (int idx = tid; idx < 8192; idx += 256) {
      int jj = idx >> 4, bb = idx & 15;
      hl[jj * 16 + (bb ^ ((jj >> 7) << 2))] = hsrc[jj * 32 + bhalf * 16 + bb];
    }
  }
  __syncthreads();
  const float bia0 = bias[j], bia1 = bias[512 + j], bia2 = bias[1024 + j], bia3 = bias[1536 + j];
  const float* WihR0 = Wih + (size_t)(j       ) * 120;
  const float* WihR1 = Wih + (size_t)(512  + j) * 120;
  const float* WihR2 = Wih + (size_t)(1024 + j) * 120;
  const float* WihR3 = Wih + (size_t)(1536 + j) * 120;
  const float* Wr0 = Wl + (j_lo * 4 + 0) * 512;
  const float* Wr1 = Wl + (j_lo * 4 + 1) * 512;
  const float* Wr2 = Wl + (j_lo * 4 + 2) * 512;
  const float* Wr3 = Wl + (j_lo * 4 + 3) * 512;
  const int bswz = b_lo ^ (quad << 2);
  const int xs = 32 * quad;
  const int xe = (quad == 3) ? 120 : (32 * quad + 32);
  const int hs = 128 * quad;
  float a0 = 0.f, a1 = 0.f, a2 = 0.f, a3 = 0.f;
  {
    const float* xg = P.audio_T + (size_t)t * 3840 + bG;
    for (int k = xs; k < xe; k += 4) {
      float4 w0 = *(const float4*)(WihR0 + k);
      float4 w1 = *(const float4*)(WihR1 + k);
      float4 w2 = *(const float4*)(WihR2 + k);
      float4 w3 = *(const float4*)(WihR3 + k);
      float x0 = xg[(k + 0) * 32], x1 = xg[(k + 1) * 32];
      float x2 = xg[(k + 2) * 32], x3 = xg[(k + 3) * 32];
      a0 += w0.x * x0 + w0.y * x1 + w0.z * x2 + w0.w * x3;
      a1 += w1.x * x0 + w1.y * x1 + w1.z * x2 + w1.w * x3;
      a2 += w2.x * x0 + w2.y * x1 + w2.z * x2 + w2.w * x3;
      a3 += w3.x * x0 + w3.y * x1 + w3.z * x2 + w3.w * x3;
    }
  }
  #pragma unroll 4
  for (int kk = 0; kk < 128; kk += 4) {
    const int k = hs + kk;
    float4 w0 = *(const float4*)(Wr0 + k);
    float4 w1 = *(const float4*)(Wr1 + k);
    float4 w2 = *(const float4*)(Wr2 + k);
    float4 w3 = *(const float4*)(Wr3 + k);
    float x0 = hl[(k + 0) * 16 + bswz], x1 = hl[(k + 1) * 16 + bswz];
    float x2 = hl[(k + 2) * 16 + bswz], x3 = hl[(k + 3) * 16 + bswz];
    a0 += w0.x * x0 + w0.y * x1 + w0.z * x2 + w0.w * x3;
    a1 += w1.x * x0 + w1.y * x1 + w1.z * x2 + w1.w * x3;
    a2 += w2.x * x0 + w2.y * x1 + w2.z * x2 + w2.w * x3;
    a3 += w3.x * x0 + w3.y * x1 + w3.z * x2 + w3.w * x3;
  }
  a0 += __shfl_xor(a0, 16); a0 += __shfl_xor(a0, 32);
  a1 += __shfl_xor(a1, 16); a1 += __shfl_xor(a1, 32);
  a2 += __shfl_xor(a2, 16); a2 += __shfl_xor(a2, 32);
  a3 += __shfl_xor(a3, 16); a3 += __shfl_xor(a3, 32);
  if (quad == 0) {
    float gi = a0 + bia0, gf = a1 + bia1, gg = a2 + bia2, go = a3 + bia3;
    const int ci = dir * 16384 + j * 32 + bG;
    float co = P.c_enc[ci];
    float cn = sigf(gf) * co + sigf(gi) * tanhf(gg);
    float hn = sigf(go) * tanhf(cn);
    P.c_enc[ci] = cn;
    P.h_enc[(size_t)(((p ^ 1) * 2 + dir)) * 16384 + j * 32 + bG] = hn;
    P.enc2[(size_t)bG * 614400 + (size_t)(dir * 512 + j) * 600 + t] = hn;
  }
}

// ---------------- key/val GEMM ----------------
struct KVP {
  const float* enc2; const float* Wk; const float* bk; const float* Wv; const float* bv;
  float* key_T; float* val;
};

__global__ __launch_bounds__(256) void k_keyval(KVP P) {
  __shared__ float As[16 * 132];
  __shared__ float Bs[16 * 132];
  const int tid = threadIdx.x, bid = blockIdx.x;
  const int mt = bid % 150, nt = bid / 150;
  const int m0 = mt * 128, n0 = nt * 128;
  const int tx = tid & 15, ty = tid >> 4;
  const int mmS = tid & 127;
  const int gmS = m0 + mmS;
  const int bS = gmS / 600, tS = gmS % 600;
  const int kkS0 = tid >> 7;
  const int nnS0 = tid >> 4;
  const int kkSB = tid & 15;
  float acc[8][8];
  #pragma unroll
  for (int i = 0; i < 8; i++)
    #pragma unroll
    for (int jj = 0; jj < 8; jj++) acc[i][jj] = 0.f;
  for (int k0 = 0; k0 < 1024; k0 += 16) {
    #pragma unroll
    for (int r = 0; r < 8; r++) {
      int kk = kkS0 + 2 * r;
      As[kk * 132 + mmS] = P.enc2[(size_t)bS * 614400 + (size_t)(k0 + kk) * 600 + tS];
    }
    #pragma unroll
    for (int r = 0; r < 8; r++) {
      int nn = nnS0 + 16 * r;
      int n = n0 + nn;
      const float* src = (n < 512) ? (P.Wk + (size_t)n * 1024) : (P.Wv + (size_t)(n - 512) * 1024);
      Bs[kkSB * 132 + nn] = src[k0 + kkSB];
    }
    __syncthreads();
    #pragma unroll
    for (int kk = 0; kk < 16; kk++) {
      float4 A0 = *(const float4*)&As[kk * 132 + ty * 8];
      float4 A1 = *(const float4*)&As[kk * 132 + ty * 8 + 4];
      float4 B0 = *(const float4*)&Bs[kk * 132 + tx * 8];
      float4 B1 = *(const float4*)&Bs[kk * 132 + tx * 8 + 4];
      float av[8] = {A0.x, A0.y, A0.z, A0.w, A1.x, A1.y, A1.z, A1.w};
      float bw[8] = {B0.x, B0.y, B0.z, B0.w, B1.x, B1.y, B1.z, B1.w};
      #pragma unroll
      for (int i = 0; i < 8; i++)
        #pragma unroll
        for (int jj = 0; jj < 8; jj++) acc[i][jj] += av[i] * bw[jj];
    }
    __syncthreads();
  }
  #pragma unroll
  for (int i = 0; i < 8; i++) {
    int gm = m0 + ty * 8 + i;
    int b = gm / 600, t = gm % 600;
    #pragma unroll
    for (int jj = 0; jj < 8; jj++) {
      int n = n0 + tx * 8 + jj;
      float bia = (n < 512) ? P.bk[n] : P.bv[n - 512];
      float v = tanhf(acc[i][jj] + bia);
      if (n < 512) P.key_T[(size_t)b * 307200 + (size_t)n * 600 + t] = v;
      else         P.val  [(size_t)b * 614400 + (size_t)t * 1024 + (n - 512)] = v;
    }
  }
}

// ---------------- decoder ----------------
struct DecP {
  const float* Wq; const float* bq;
  const float* Wih_d; const float* Whh_d; const float* b_d;
  const float* Wc; const float* bc; const float* E;
  const int* flen;
  const float* key_T; const float* val;
  float* h_d; float* c_d; float* last; float* q; float* ctx;
  float* scores; float* stats;
  float* out;
  u32* bar;
};

// ---- persistent cooperative decoder (256 blocks x 256) ----
__global__ __launch_bounds__(256) void k_decoder(DecP P) {
  __shared__ float sm[16384];   // 64 KiB, reused per phase
  const int tid = threadIdx.x, bid = blockIdx.x;
  u32 epoch = 0;
  u32* ctr = P.bar + 256;

  auto gsync = [&]() {
    __syncthreads();
    epoch++;
    if (tid == 0) {
      __threadfence();
      __hip_atomic_fetch_add(ctr, 1u, __ATOMIC_ACQ_REL, __HIP_MEMORY_SCOPE_AGENT);
      u32 tgt = epoch * 256u;
      while (__hip_atomic_load(ctr, __ATOMIC_ACQUIRE, __HIP_MEMORY_SCOPE_AGENT) < tgt)
        __builtin_amdgcn_s_sleep(2);
      __threadfence();
    }
    __syncthreads();
  };

  auto phase_gates = [&](int i) {
    const int p = i & 1;
    const int bq4 = bid >> 6;
    const int jblk = bid & 63;
    const int b_lo = tid & 7;
    const int quad = (tid >> 3) & 3;
    const int j_lo = tid >> 5;
    const int bG = bq4 * 8 + b_lo;
    const int j = jblk * 8 + j_lo;
    const float* hsrc = P.h_d + p * 16384;
    for (int idx = tid; idx < 8 * 2048; idx += 256) {
      int bb = idx >> 11, c = idx & 2047;
      int gb = bq4 * 8 + bb;
      float v;
      if (c < 512)       v = P.last[gb * 512 + c];
      else if (c < 1536) v = P.ctx[gb * 1024 + (c - 512)];
      else               v = hsrc[gb * 512 + (c - 1536)];
      sm[bb * 2048 + (c ^ (bb << 2))] = v;
    }
    __syncthreads();
    const int k0 = quad << 9;
    const float* wbp; int rs, ko;
    if (quad < 3) { wbp = P.Wih_d; rs = 1536; ko = k0; }
    else          { wbp = P.Whh_d; rs = 512;  ko = 0;  }
    const float* r0 = wbp + (size_t)(j       ) * rs + ko;
    const float* r1 = wbp + (size_t)(512  + j) * rs + ko;
    const float* r2 = wbp + (size_t)(1024 + j) * rs + ko;
    const float* r3 = wbp + (size_t)(1536 + j) * rs + ko;
    const float* xb = sm + b_lo * 2048 + k0;
    const int xo = b_lo << 2;
    float a0 = 0.f, a1 = 0.f, a2 = 0.f, a3 = 0.f;
    #pragma unroll 4
    for (int k = 0; k < 512; k += 4) {
      float4 w0 = *(const float4*)(r0 + k);
      float4 w1 = *(const float4*)(r1 + k);
      float4 w2 = *(const float4*)(r2 + k);
      float4 w3 = *(const float4*)(r3 + k);
      float4 x  = *(const float4*)(xb + (k ^ xo));
      a0 += w0.x * x.x + w0.y * x.y + w0.z * x.z + w0.w * x.w;
      a1 += w1.x * x.x + w1.y * x.y + w1.z * x.z + w1.w * x.w;
      a2 += w2.x * x.x + w2.y * x.y + w2.z * x.z + w2.w * x.w;
      a3 += w3.x * x.x + w3.y * x.y + w3.z * x.z + w3.w * x.w;
    }
    a0 += __shfl_xor(a0, 8); a0 += __shfl_xor(a0, 16);
    a1 += __shfl_xor(a1, 8); a1 += __shfl_xor(a1, 16);
    a2 += __shfl_xor(a2, 8); a2 += __shfl_xor(a2, 16);
    a3 += __shfl_xor(a3, 8); a3 += __shfl_xor(a3, 16);
    if (quad == 0) {
      float gi = a0 + P.b_d[j];
      float gf = a1 + P.b_d[512 + j];
      float gg = a2 + P.b_d[1024 + j];
      float go = a3 + P.b_d[1536 + j];
      int ci = bG * 512 + j;
      float co = P.c_d[ci];
      float cn = sigf(gf) * co + sigf(gi) * tanhf(gg);
      float hn = sigf(go) * tanhf(cn);
      P.c_d[ci] = cn;
      P.h_d[(p ^ 1) * 16384 + ci] = hn;
    }
  };

  auto phase_logits_q = [&](int i) {
    const int pn = (i & 1) ^ 1;
    const float* hsrc = P.h_d + pn * 16384;
    for (int idx = tid; idx < 16384; idx += 256) {
      int bb = idx >> 9, k = idx & 511;
      sm[bb * 512 + (k ^ ((bb & 7) << 2))] = hsrc[idx];
    }
    __syncthreads();
    if (bid < 224) {
      if (i < 0) return;
      for (int pidx = bid * 256 + tid; pidx < 65536; pidx += 57344) {
        int bb = pidx & 31;
        int v0 = (pidx >> 5) << 1;
        const float* w0 = P.Wc + (size_t)v0 * 512;
        const float* w1 = w0 + 512;
        const float* hbp = sm + bb * 512;
        const int xo = (bb & 7) << 2;
        float s0 = 0.f, s1 = 0.f;
        #pragma unroll 4
        for (int k = 0; k < 512; k += 4) {
          float4 A0 = *(const float4*)(w0 + k);
          float4 A1 = *(const float4*)(w1 + k);
          int kx = k ^ xo;
          float h0 = hbp[kx], h1 = hbp[kx + 1], h2 = hbp[kx + 2], h3 = hbp[kx + 3];
          s0 += A0.x * h0 + A0.y * h1 + A0.z * h2 + A0.w * h3;
          s1 += A1.x * h0 + A1.y * h1 + A1.z * h2 + A1.w * h3;
        }
        size_t o = (size_t)bb * 491520 + (size_t)i * 4096 + v0;
        P.out[o]     = s0 + P.bc[v0];
        P.out[o + 1] = s1 + P.bc[v0 + 1];
      }
    } else {
      int pidx = (bid - 224) * 256 + tid;
      int bb = pidx & 31;
      int d0 = (pidx >> 5) << 1;
      const float* w0 = P.Wq + (size_t)d0 * 512;
      const float* w1 = w0 + 512;
      const float* hbp = sm + bb * 512;
      const int xo = (bb & 7) << 2;
      float s0 = 0.f, s1 = 0.f;
      #pragma unroll 4
      for (int k = 0; k < 512; k += 4) {
        float4 A0 = *(const float4*)(w0 + k);
        float4 A1 = *(const float4*)(w1 + k);
        int kx = k ^ xo;
        float h0 = hbp[kx], h1 = hbp[kx + 1], h2 = hbp[kx + 2], h3 = hbp[kx + 3];
        s0 += A0.x * h0 + A0.y * h1 + A0.z * h2 + A0.w * h3;
        s1 += A1.x * h0 + A1.y * h1 + A1.z * h2 + A1.w * h3;
      }
      P.q[bb * 512 + d0]     = tanhf(s0 + P.bq[d0]);
      P.q[bb * 512 + d0 + 1] = tanhf(s1 + P.bq[d0 + 1]);
    }
  };

  auto phase_amax_scores = [&](int i, bool do_scores) {
    if (bid < 32) {
      if (i < 0) return;
      const float* row = P.out + (size_t)bid * 491520 + (size_t)i * 4096;
      float bv = -INFINITY; int bi = 0;
      for (int v = tid; v < 4096; v += 256) {
        float x = row[v];
        if (x > bv) { bv = x; bi = v; }
      }
      float* smax = sm;
      int* sidx = (int*)(sm + 256);
      smax[tid] = bv; sidx[tid] = bi;
      __syncthreads();
      for (int off = 128; off > 0; off >>= 1) {
        if (tid < off) {
          float ov = smax[tid + off]; int oi = sidx[tid + off];
          if (ov > smax[tid] || (ov == smax[tid] && oi < sidx[tid])) { smax[tid] = ov; sidx[tid] = oi; }
        }
        __syncthreads();
      }
      int widx = sidx[0];
      for (int k = tid; k < 512; k += 256) P.last[bid * 512 + k] = P.E[(size_t)widx * 512 + k];
    } else if (bid < 64) {
      if (!do_scores) return;
      int bb = bid - 32;
      float* ql  = sm;
      float* part = sm + 512;
      float* red = sm + 2368;
      for (int k = tid; k < 512; k += 256) ql[k] = P.q[bb * 512 + k];
      __syncthreads();
      if (tid < 225) {
        int tg = tid % 75, kq = tid / 75;
        int t0 = tg * 8;
        int kb_ = (kq == 0) ? 0   : ((kq == 1) ? 170 : 340);
        int ke_ = (kq == 0) ? 170 : ((kq == 1) ? 340 : 512);
        const float* kp = P.key_T + (size_t)bb * 307200 + t0;
        float s0=0,s1=0,s2=0,s3=0,s4=0,s5=0,s6=0,s7=0;
        for (int k = kb_; k < ke_; k++) {
          float qv = ql[k];
          const float* kr = kp + (size_t)k * 600;
          float4 u0 = *(const float4*)(kr);
          float4 u1 = *(const float4*)(kr + 4);
          s0 += qv * u0.x; s1 += qv * u0.y; s2 += qv * u0.z; s3 += qv * u0.w;
          s4 += qv * u1.x; s5 += qv * u1.y; s6 += qv * u1.z; s7 += qv * u1.w;
        }
        float* pp = part + kq * 600 + t0;
        pp[0]=s0; pp[1]=s1; pp[2]=s2; pp[3]=s3; pp[4]=s4; pp[5]=s5; pp[6]=s6; pp[7]=s7;
      }
      __syncthreads();
      int len = P.flen[bb];
      float sc0, sc1, sc2;
      {
        int t = tid;
        float s = part[t] + part[600 + t] + part[1200 + t];
        sc0 = (t < len) ? 2.0f * s : -1e30f;
        P.scores[bb * 600 + t] = sc0;
      }
      {
        int t = tid + 256;
        float s = part[t] + part[600 + t] + part[1200 + t];
        sc1 = (t < len) ? 2.0f * s : -1e30f;
        P.scores[bb * 600 + t] = sc1;
      }
      bool has2 = (tid < 88);
      sc2 = -INFINITY;
      if (has2) {
        int t = tid + 512;
        float s = part[t] + part[600 + t] + part[1200 + t];
        sc2 = (t < len) ? 2.0f * s : -1e30f;
        P.scores[bb * 600 + t] = sc2;
      }
      float lm = fmaxf(fmaxf(sc0, sc1), sc2);
      red[tid] = lm;
      __syncthreads();
      for (int off = 128; off > 0; off >>= 1) {
        if (tid < off) red[tid] = fmaxf(red[tid], red[tid + off]);
        __syncthreads();
      }
      float m = red[0];
      __syncthreads();
      float ls = expf(sc0 - m) + expf(sc1 - m) + (has2 ? expf(sc2 - m) : 0.f);
      red[tid] = ls;
      __syncthreads();
      for (int off = 128; off > 0; off >>= 1) {
        if (tid < off) red[tid] += red[tid + off];
        __syncthreads();
      }
      if (tid == 0) { P.stats[bb * 2] = m; P.stats[bb * 2 + 1] = red[0]; }
    }
  };

  auto phase_ctx = [&](int att_i) {
    int bb = bid >> 3, wblk = bid & 7;
    float M = P.stats[bb * 2], L = P.stats[bb * 2 + 1];
    float invL = 1.0f / L;
    float* pl = sm;
    for (int t = tid; t < 600; t += 256) {
      float pv = expf(P.scores[bb * 600 + t] - M) * invL;
      pl[t] = pv;
      if (wblk == 0) P.out[15728640ull + (size_t)bb * 72000 + (size_t)att_i * 600 + t] = pv;
    }
    __syncthreads();
    int w = (wblk << 7) + (tid & 127);
    int th = tid >> 7;
    const float* vb = P.val + (size_t)bb * 614400 + w;
    float acc = 0.f;
    #pragma unroll 4
    for (int t = th * 300; t < th * 300 + 300; t++) acc += pl[t] * vb[(size_t)t * 1024];
    float* red = sm + 640;
    red[tid] = acc;
    __syncthreads();
    if (tid < 128) P.ctx[bb * 1024 + (wblk << 7) + tid] = red[tid] + red[tid + 128];
  };

  phase_logits_q(-1);
  gsync();
  phase_amax_scores(-1, true);
  gsync();
  phase_ctx(0);
  gsync();
  for (int i = 0; i < 120; i++) {
    phase_gates(i);
    gsync();
    phase_logits_q(i);
    gsync();
    phase_amax_scores(i, i < 119);
    gsync();
    if (i < 119) phase_ctx(i + 1);
    gsync();
  }
}

// ---- fallback decoder kernels (one phase per launch, r2-proven) ----
__global__ __launch_bounds__(256) void k_dec_gates(DecP P, int i) {
  __shared__ float sm[16384];
  const int tid = threadIdx.x, bid = blockIdx.x;
  const int p = i & 1;
  const int bq4 = bid >> 6;
  const int jblk = bid & 63;
  const int b_lo = tid & 7;
  const int quad = (tid >> 3) & 3;
  const int j_lo = tid >> 5;
  const int bG = bq4 * 8 + b_lo;
  const int j = jblk * 8 + j_lo;
  const float* hsrc = P.h_d + p * 16384;
  for (int idx = tid; idx < 8 * 2048; idx += 256) {
    int bb = idx >> 11, c = idx & 2047;
    int gb = bq4 * 8 + bb;
    float v;
    if (c < 512)       v = P.last[gb * 512 + c];
    else if (c < 1536) v = P.ctx[gb * 1024 + (c - 512)];
    else               v = hsrc[gb * 512 + (c - 1536)];
    sm[bb * 2048 + (c ^ (bb << 2))] = v;
  }
  __syncthreads();
  const int k0 = quad << 9;
  const float* wbp; int rs, ko;
  if (quad < 3) { wbp = P.Wih_d; rs = 1536; ko = k0; }
  else          { wbp = P.Whh_d; rs = 512;  ko = 0;  }
  const float* r0 = wbp + (size_t)(j       ) * rs + ko;
  const float* r1 = wbp + (size_t)(512  + j) * rs + ko;
  const float* r2 = wbp + (size_t)(1024 + j) * rs + ko;
  const float* r3 = wbp + (size_t)(1536 + j) * rs + ko;
  const float* xb = sm + b_lo * 2048 + k0;
  const int xo = b_lo << 2;
  float a0 = 0.f, a1 = 0.f, a2 = 0.f, a3 = 0.f;
  #pragma unroll 4
  for (int k = 0; k < 512; k += 4) {
    float4 w0 = *(const float4*)(r0 + k);
    float4 w1 = *(const float4*)(r1 + k);
    float4 w2 = *(const float4*)(r2 + k);
    float4 w3 = *(const float4*)(r3 + k);
    float4 x  = *(const float4*)(xb + (k ^ xo));
    a0 += w0.x * x.x + w0.y * x.y + w0.z * x.z + w0.w * x.w;
    a1 += w1.x * x.x + w1.y * x.y + w1.z * x.z + w1.w * x.w;
    a2 += w2.x * x.x + w2.y * x.y + w2.z * x.z + w2.w * x.w;
    a3 += w3.x * x.x + w3.y * x.y + w3.z * x.z + w3.w * x.w;
  }
  a0 += __shfl_xor(a0, 8); a0 += __shfl_xor(a0, 16);
  a1 += __shfl_xor(a1, 8); a1 += __shfl_xor(a1, 16);
  a2 += __shfl_xor(a2, 8); a2 += __shfl_xor(a2, 16);
  a3 += __shfl_xor(a3, 8); a3 += __shfl_xor(a3, 16);
  if (quad == 0) {
    float gi = a0 + P.b_d[j];
    float gf = a1 + P.b_d[512 + j];
    float gg = a2 + P.b_d[1024 + j];
    float go = a3 + P.b_d[1536 + j];
    int ci = bG * 512 + j;
    float co = P.c_d[ci];
    float cn = sigf(gf) * co + sigf(gi) * tanhf(gg);
    float hn = sigf(go) * tanhf(cn);
    P.c_d[ci] = cn;
    P.h_d[(p ^ 1) * 16384 + ci] = hn;
  }
}

__global__ __launch_bounds__(256) void k_dec_logits_q(DecP P, int i) {
  __shared__ float sm[16384];
  const int tid = threadIdx.x, bid = blockIdx.x;
  const int pn = (i & 1) ^ 1;
  const float* hsrc = P.h_d + pn * 16384;
  for (int idx = tid; idx < 16384; idx += 256) {
    int bb = idx >> 9, k = idx & 511;
    sm[bb * 512 + (k ^ ((bb & 7) << 2))] = hsrc[idx];
  }
  __syncthreads();
  if (bid < 224) {
    if (i < 0) return;
    for (int pidx = bid * 256 + tid; pidx < 65536; pidx += 57344) {
      int bb = pidx & 31;
      int v0 = (pidx >> 5) << 1;
      const float* w0 = P.Wc + (size_t)v0 * 512;
      const float* w1 = w0 + 512;
      const float* hbp = sm + bb * 512;
      const int xo = (bb & 7) << 2;
      float s0 = 0.f, s1 = 0.f;
      #pragma unroll 4
      for (int k = 0; k < 512; k += 4) {
        float4 A0 = *(const float4*)(w0 + k);
        float4 A1 = *(const float4*)(w1 + k);
        int kx = k ^ xo;
        float h0 = hbp[kx], h1 = hbp[kx + 1], h2 = hbp[kx + 2], h3 = hbp[kx + 3];
        s0 += A0.x * h0 + A0.y * h1 + A0.z * h2 + A0.w * h3;
        s1 += A1.x * h0 + A1.y * h1 + A1.z * h2 + A1.w * h3;
      }
      size_t o = (size_t)bb * 491520 + (size_t)i * 4096 + v0;
      P.out[o]     = s0 + P.bc[v0];
      P.out[o + 1] = s1 + P.bc[v0 + 1];
    }
  } else {
    int pidx = (bid - 224) * 256 + tid;
    int bb = pidx & 31;
    int d0 = (pidx >> 5) << 1;
    const float* w0 = P.Wq + (size_t)d0 * 512;
    const float* w1 = w0 + 512;
    const float* hbp = sm + bb * 512;
    const int xo = (bb & 7) << 2;
    float s0 = 0.f, s1 = 0.f;
    #pragma unroll 4
    for (int k = 0; k < 512; k += 4) {
      float4 A0 = *(const float4*)(w0 + k);
      float4 A1 = *(const float4*)(w1 + k);
      int kx = k ^ xo;
      float h0 = hbp[kx], h1 = hbp[kx + 1], h2 = hbp[kx + 2], h3 = hbp[kx + 3];
      s0 += A0.x * h0 + A0.y * h1 + A0.z * h2 + A0.w * h3;
      s1 += A1.x * h0 + A1.y * h1 + A1.z * h2 + A1.w * h3;
    }
    P.q[bb * 512 + d0]     = tanhf(s0 + P.bq[d0]);
    P.q[bb * 512 + d0 + 1] = tanhf(s1 + P.bq[d0 + 1]);
  }
}

__global__ __launch_bounds__(256) void k_dec_amax(DecP P, int i, int do_scores) {
  __shared__ float sm[2600];
  const int tid = threadIdx.x, bid = blockIdx.x;
  if (bid < 32) {
    if (i < 0) return;
    const float* row = P.out + (size_t)bid * 491520 + (size_t)i * 4096;
    float bv = -INFINITY; int bi = 0;
    for (int v = tid; v < 4096; v += 256) {
      float x = row[v];
      if (x > bv) { bv = x; bi = v; }
    }
    float* smax = sm;
    int* sidx = (int*)(sm + 256);
    smax[tid] = bv; sidx[tid] = bi;
    __syncthreads();
    for (int off = 128; off > 0; off >>= 1) {
      if (tid < off) {
        float ov = smax[tid + off]; int oi = sidx[tid + off];
        if (ov > smax[tid] || (ov == smax[tid] && oi < sidx[tid])) { smax[tid] = ov; sidx[tid] = oi; }
      }
      __syncthreads();
    }
    int widx = sidx[0];
    for (int k = tid; k < 512; k += 256) P.last[bid * 512 + k] = P.E[(size_t)widx * 512 + k];
  } else {
    if (!do_scores) return;
    int bb = bid - 32;
    float* ql  = sm;
    float* part = sm + 512;
    float* red = sm + 2340;
    for (int k = tid; k < 512; k += 256) ql[k] = P.q[bb * 512 + k];
    __syncthreads();
    if (tid < 225) {
      int tg = tid % 75, kq = tid / 75;
      int t0 = tg * 8;
      int kb_ = (kq == 0) ? 0   : ((kq == 1) ? 170 : 340);
      int ke_ = (kq == 0) ? 170 : ((kq == 1) ? 340 : 512);
      const float* kp = P.key_T + (size_t)bb * 307200 + t0;
      float s0=0,s1=0,s2=0,s3=0,s4=0,s5=0,s6=0,s7=0;
      for (int k = kb_; k < ke_; k++) {
        float qv = ql[k];
        const float* kr = kp + (size_t)k * 600;
        float4 u0 = *(const float4*)(kr);
        float4 u1 = *(const float4*)(kr + 4);
        s0 += qv * u0.x; s1 += qv * u0.y; s2 += qv * u0.z; s3 += qv * u0.w;
        s4 += qv * u1.x; s5 += qv * u1.y; s6 += qv * u1.z; s7 += qv * u1.w;
      }
      float* pp = part + kq * 600 + t0;
      pp[0]=s0; pp[1]=s1; pp[2]=s2; pp[3]=s3; pp[4]=s4; pp[5]=s5; pp[6]=s6; pp[7]=s7;
    }
    __syncthreads();
    int len = P.flen[bb];
    float sc0, sc1, sc2;
    {
      int t = tid;
      float s = part[t] + part[600 + t] + part[1200 + t];
      sc0 = (t < len) ? 2.0f * s : -1e30f;
      P.scores[bb * 600 + t] = sc0;
    }
    {
      int t = tid + 256;
      float s = part[t] + part[600 + t] + part[1200 + t];
      sc1 = (t < len) ? 2.0f * s : -1e30f;
      P.scores[bb * 600 + t] = sc1;
    }
    bool has2 = (tid < 88);
    sc2 = -INFINITY;
    if (has2) {
      int t = tid + 512;
      float s = part[t] + part[600 + t] + part[1200 + t];
      sc2 = (t < len) ? 2.0f * s : -1e30f;
      P.scores[bb * 600 + t] = sc2;
    }
    float lm = fmaxf(fmaxf(sc0, sc1), sc2);
    red[tid] = lm;
    __syncthreads();
    for (int off = 128; off > 0; off >>= 1) {
      if (tid < off) red[tid] = fmaxf(red[tid], red[tid + off]);
      __syncthreads();
    }
    float m = red[0];
    __syncthreads();
    float ls = expf(sc0 - m) + expf(sc1 - m) + (has2 ? expf(sc2 - m) : 0.f);
    red[tid] = ls;
    __syncthreads();
    for (int off = 128; off > 0; off >>= 1) {
      if (tid < off) red[tid] += red[tid + off];
      __syncthreads();
    }
    if (tid == 0) { P.stats[bb * 2] = m; P.stats[bb * 2 + 1] = red[0]; }
  }
}

__global__ __launch_bounds__(256) void k_dec_ctx(DecP P, int att_i) {
  __shared__ float sm[896];
  const int tid = threadIdx.x, bid = blockIdx.x;
  int bb = bid >> 3, wblk = bid & 7;
  float M = P.stats[bb * 2], L = P.stats[bb * 2 + 1];
  float invL = 1.0f / L;
  float* pl = sm;
  for (int t = tid; t < 600; t += 256) {
    float pv = expf(P.scores[bb * 600 + t] - M) * invL;
    pl[t] = pv;
    if (wblk == 0) P.out[15728640ull + (size_t)bb * 72000 + (size_t)att_i * 600 + t] = pv;
  }
  __syncthreads();
  int w = (wblk << 7) + (tid & 127);
  int th = tid >> 7;
  const float* vb = P.val + (size_t)bb * 614400 + w;
  float acc = 0.f;
  #pragma unroll 4
  for (int t = th * 300; t < th * 300 + 300; t++) acc += pl[t] * vb[(size_t)t * 1024];
  float* red = sm + 640;
  red[tid] = acc;
  __syncthreads();
  if (tid < 128) P.ctx[bb * 1024 + (wblk << 7) + tid] = red[tid] + red[tid + 128];
}

// ---------------- launch ----------------
extern "C" void kernel_launch(void* const* d_in, const int* in_sizes, int n_in,
                              void* d_out, int out_size, void* d_ws, size_t ws_size,
                              hipStream_t stream) {
  const float* audio = (const float*)d_in[0];
  const float* Wih_f = (const float*)d_in[1];
  const float* Whh_f = (const float*)d_in[2];
  const float* b_f   = (const float*)d_in[3];
  const float* Wih_b = (const float*)d_in[4];
  const float* Whh_b = (const float*)d_in[5];
  const float* b_b   = (const float*)d_in[6];
  const float* Wq    = (const float*)d_in[7];
  const float* bq    = (const float*)d_in[8];
  const float* Wk    = (const float*)d_in[9];
  const float* bk    = (const float*)d_in[10];
  const float* Wv    = (const float*)d_in[11];
  const float* bv    = (const float*)d_in[12];
  const float* Wih_d = (const float*)d_in[13];
  const float* Whh_d = (const float*)d_in[14];
  const float* b_d   = (const float*)d_in[15];
  const float* Wc    = (const float*)d_in[16];
  const float* bc    = (const float*)d_in[17];
  const float* E     = (const float*)d_in[18];
  const int*   flen  = (const int*)d_in[19];
  float* out = (float*)d_out;
  char* ws = (char*)d_ws;

  u32*   bar     = (u32*)  (ws + OFF_BAR);
  float* h_enc   = (float*)(ws + OFF_HENC);
  float* c_enc   = (float*)(ws + OFF_CENC);
  float* h_d     = (float*)(ws + OFF_HD);
  float* c_d     = (float*)(ws + OFF_CD);
  float* last    = (float*)(ws + OFF_LAST);
  float* qbuf    = (float*)(ws + OFF_Q);
  float* ctx     = (float*)(ws + OFF_CTX);
  float* scores  = (float*)(ws + OFF_SCORES);
  float* stats   = (float*)(ws + OFF_STATS);
  float* audio_T = (float*)(ws + OFF_AUDIOT);
  float* enc2    = (float*)(ws + OFF_ENC2);
  float* key_T   = (float*)(ws + OFF_KEYT);
  float* val     = (float*)(ws + OFF_VAL);

  hipMemsetAsync(ws, 0, STATE_BYTES, stream);
  k_init_last<<<64, 256, 0, stream>>>(E, last);
  k_prep_audio<<<(T_ * FIN_ * 32 + 255) / 256, 256, 0, stream>>>(audio, audio_T);

  EncP ep{audio_T, Wih_f, Whh_f, b_f, Wih_b, Whh_b, b_b, h_enc, c_enc, enc2, bar};
  void* ea[] = { &ep };
  hipError_t ee = hipLaunchCooperativeKernel((const void*)k_encoder, dim3(256), dim3(256), ea, 0, stream);
  if (ee != hipSuccess) {
    (void)hipGetLastError();
    for (int s = 0; s < 600; s++) k_enc_step<<<512, 256, 0, stream>>>(ep, s);
  }

  KVP kp{enc2, Wk, bk, Wv, bv, key_T, val};
  k_keyval<<<1800, 256, 0, stream>>>(kp);

  DecP dp{Wq, bq, Wih_d, Whh_d, b_d, Wc, bc, E, flen, key_T, val,
          h_d, c_d, last, qbuf, ctx, scores, stats, out, bar};
  void* da[] = { &dp };
  hipError_t ed = hipLaunchCooperativeKernel((const void*)k_decoder, dim3(256), dim3(256), da, 0, stream);
  if (ed != hipSuccess) {
    (void)hipGetLastError();
    k_dec_logits_q<<<256, 256, 0, stream>>>(dp, -1);
    k_dec_amax<<<64, 256, 0, stream>>>(dp, -1, 1);
    k_dec_ctx<<<256, 256, 0, stream>>>(dp, 0);
    for (int i = 0; i < 120; i++) {
      k_dec_gates<<<256, 256, 0, stream>>>(dp, i);
      k_dec_logits_q<<<256, 256, 0, stream>>>(dp, i);
      k_dec_amax<<<64, 256, 0, stream>>>(dp, i, (i < 119) ? 1 : 0);
      if (i < 119) k_dec_ctx<<<256, 256, 0, stream>>>(dp, i + 1);
    }
  }
}

// Round 5
// 58273.651 us; speedup vs baseline: 1.2963x; 1.2963x over previous
//
#include <hip/hip_runtime.h>
#include <math.h>

typedef unsigned int u32;
typedef float nt_f4 __attribute__((ext_vector_type(4)));

#define T_    600
#define FIN_  120

// ---- ws byte offsets ----
#define OFF_BAR      0ull          // 2048 B: arrive[256] @0, dec_flag @bar[256], enc_flag[g] @bar[257+g]
#define OFF_HENC     2048ull       // [2 parity][2 dir][512][32] f32 = 262144
#define OFF_CENC     264192ull     // (unused; layout compat)
#define OFF_HD       395264ull     // [2 parity][32][512] = 131072
#define OFF_CD       526336ull     // [32][512] = 65536
#define STATE_BYTES  591872ull     // memset-0 region
#define OFF_LAST     591872ull     // [32][512]
#define OFF_Q        657408ull     // [32][512]
#define OFF_CTX      722944ull     // [32][1024]
#define OFF_SCORES   854016ull     // [32][600]
#define OFF_STATS    930816ull     // [32][8] chunk maxes (1024 B)
#define OFF_AUDIOT   931840ull     // [600][120][32]
#define OFF_ENC2     10147840ull   // [32][1024][600]
#define OFF_KEYT     88791040ull   // key_bt [32][600][512]
#define OFF_VAL      128112640ull  // val [32][600][1024]

__device__ __forceinline__ float sigf(float x) { return 1.0f / (1.0f + expf(-x)); }
__device__ __forceinline__ u32 umin4(u32 a, u32 b, u32 c, u32 d) {
  u32 x = a < b ? a : b; u32 y = c < d ? c : d; return x < y ? x : y;
}

// ---------------- prep ----------------
__global__ __launch_bounds__(256) void k_prep_audio(const float* __restrict__ audio,
                                                    float* __restrict__ audio_T) {
  int idx = blockIdx.x * 256 + threadIdx.x;
  if (idx >= T_ * FIN_ * 32) return;
  int b = idx & 31;
  int r = idx >> 5;
  int f = r % FIN_;
  int t = r / FIN_;
  audio_T[idx] = audio[(size_t)b * (T_ * FIN_) + t * FIN_ + f];
}

__global__ __launch_bounds__(256) void k_init_last(const float* __restrict__ E,
                                                   float* __restrict__ last) {
  int idx = blockIdx.x * 256 + threadIdx.x;
  if (idx < 32 * 512) last[idx] = E[idx & 511];
}

// ---------------- persistent cooperative encoder (256 blocks x 256) ----------------
struct EncP {
  const float* audio_T;
  const float* Wih_f; const float* Whh_f; const float* b_f;
  const float* Wih_b; const float* Whh_b; const float* b_b;
  float* h_enc; float* c_enc; float* enc2;
  u32* bar;
};

__global__ __launch_bounds__(256) void k_encoder(EncP P) {
  __shared__ float hl[8192];          // [512 j][16 b]
  const int tid = threadIdx.x, bid = blockIdx.x;
  const int grp = bid >> 6;           // 0..3 : dir*2+bhalf
  const int dir = grp >> 1, bhalf = grp & 1;
  const int jblk = bid & 63;
  const int b_lo = tid & 15;
  const int half = (tid >> 4) & 1;
  const int j_lo = tid >> 5;          // 0..7
  const int j = jblk * 8 + j_lo;
  const int bG = bhalf * 16 + b_lo;
  const float* Wih  = dir ? P.Wih_b : P.Wih_f;
  const float* Whh  = dir ? P.Whh_b : P.Whh_f;
  const float* bias = dir ? P.b_b   : P.b_f;
  u32* arrive = P.bar + grp * 64;
  u32* flag   = P.bar + 257 + grp;

  const float* WihR0 = Wih + (size_t)(j       ) * 120 + half * 60;
  const float* WihR1 = Wih + (size_t)(512  + j) * 120 + half * 60;
  const float* WihR2 = Wih + (size_t)(1024 + j) * 120 + half * 60;
  const float* WihR3 = Wih + (size_t)(1536 + j) * 120 + half * 60;
  const float* WhhR0 = Whh + (size_t)(j       ) * 512 + half * 256;
  const float* WhhR1 = Whh + (size_t)(512  + j) * 512 + half * 256;
  const float* WhhR2 = Whh + (size_t)(1024 + j) * 512 + half * 256;
  const float* WhhR3 = Whh + (size_t)(1536 + j) * 512 + half * 256;
  const float bia0 = bias[j], bia1 = bias[512 + j], bia2 = bias[1024 + j], bia3 = bias[1536 + j];

  float creg = 0.f;

  for (int s = 0; s < 600; s++) {
    const int t = dir ? (599 - s) : s;
    const int p = s & 1;
    {
      const float* hsrc = P.h_enc + (size_t)(p * 2 + dir) * 16384 + bhalf * 16;
      for (int idx = tid; idx < 8192; idx += 256) {
        int jj = idx >> 4, bb = idx & 15;
        hl[jj * 16 + bb] = hsrc[jj * 32 + bb];
      }
    }
    __syncthreads();

    float a0 = 0.f, a1 = 0.f, a2 = 0.f, a3 = 0.f;
    {
      const float* xg = P.audio_T + (size_t)t * 3840 + half * 1920 + bG;
      for (int kl = 0; kl < 60; kl += 4) {
        float4 w0 = *(const float4*)(WihR0 + kl);
        float4 w1 = *(const float4*)(WihR1 + kl);
        float4 w2 = *(const float4*)(WihR2 + kl);
        float4 w3 = *(const float4*)(WihR3 + kl);
        float x0 = xg[(kl + 0) * 32], x1 = xg[(kl + 1) * 32];
        float x2 = xg[(kl + 2) * 32], x3 = xg[(kl + 3) * 32];
        a0 += w0.x * x0 + w0.y * x1 + w0.z * x2 + w0.w * x3;
        a1 += w1.x * x0 + w1.y * x1 + w1.z * x2 + w1.w * x3;
        a2 += w2.x * x0 + w2.y * x1 + w2.z * x2 + w2.w * x3;
        a3 += w3.x * x0 + w3.y * x1 + w3.z * x2 + w3.w * x3;
      }
    }
    {
      const float* hb = hl + half * 4096 + b_lo;
      #pragma unroll 4
      for (int kl = 0; kl < 256; kl += 4) {
        float4 w0 = *(const float4*)(WhhR0 + kl);
        float4 w1 = *(const float4*)(WhhR1 + kl);
        float4 w2 = *(const float4*)(WhhR2 + kl);
        float4 w3 = *(const float4*)(WhhR3 + kl);
        float x0 = hb[(kl + 0) * 16], x1 = hb[(kl + 1) * 16];
        float x2 = hb[(kl + 2) * 16], x3 = hb[(kl + 3) * 16];
        a0 += w0.x * x0 + w0.y * x1 + w0.z * x2 + w0.w * x3;
        a1 += w1.x * x0 + w1.y * x1 + w1.z * x2 + w1.w * x3;
        a2 += w2.x * x0 + w2.y * x1 + w2.z * x2 + w2.w * x3;
        a3 += w3.x * x0 + w3.y * x1 + w3.z * x2 + w3.w * x3;
      }
    }
    a0 += __shfl_xor(a0, 16);
    a1 += __shfl_xor(a1, 16);
    a2 += __shfl_xor(a2, 16);
    a3 += __shfl_xor(a3, 16);
    if (half == 0) {
      float gi = a0 + bia0, gf = a1 + bia1, gg = a2 + bia2, go = a3 + bia3;
      creg = sigf(gf) * creg + sigf(gi) * tanhf(gg);
      float hn = sigf(go) * tanhf(creg);
      P.h_enc[(size_t)((p ^ 1) * 2 + dir) * 16384 + j * 32 + bG] = hn;
      P.enc2[(size_t)bG * 614400 + (size_t)(dir * 512 + j) * 600 + t] = hn;
    }
    // ---- flag barrier over 64 blocks of this group ----
    __syncthreads();
    const u32 target = (u32)(s + 1);
    if (tid == 0) {
      __threadfence();
      __hip_atomic_store(&arrive[jblk], target, __ATOMIC_RELEASE, __HIP_MEMORY_SCOPE_AGENT);
    }
    if (jblk == (s & 63)) {
      if (tid < 16) {
        const int base = tid * 4;
        for (;;) {
          u32 a0_ = __hip_atomic_load(&arrive[base + 0], __ATOMIC_RELAXED, __HIP_MEMORY_SCOPE_AGENT);
          u32 a1_ = __hip_atomic_load(&arrive[base + 1], __ATOMIC_RELAXED, __HIP_MEMORY_SCOPE_AGENT);
          u32 a2_ = __hip_atomic_load(&arrive[base + 2], __ATOMIC_RELAXED, __HIP_MEMORY_SCOPE_AGENT);
          u32 a3_ = __hip_atomic_load(&arrive[base + 3], __ATOMIC_RELAXED, __HIP_MEMORY_SCOPE_AGENT);
          if (__all(umin4(a0_, a1_, a2_, a3_) >= target)) break;
          __builtin_amdgcn_s_sleep(1);
        }
        if (tid == 0) {
          __threadfence();
          __hip_atomic_store(flag, target, __ATOMIC_RELEASE, __HIP_MEMORY_SCOPE_AGENT);
        }
      }
    }
    if (tid == 0) {
      while (__hip_atomic_load(flag, __ATOMIC_ACQUIRE, __HIP_MEMORY_SCOPE_AGENT) < target)
        __builtin_amdgcn_s_sleep(2);
      __threadfence();
    }
    __syncthreads();
  }
}

// ---------------- key/val GEMM: key -> [b][t][k], val -> [b][t][w] ----------------
struct KVP {
  const float* enc2; const float* Wk; const float* bk; const float* Wv; const float* bv;
  float* key_bt; float* val;
};

__global__ __launch_bounds__(256) void k_keyval(KVP P) {
  __shared__ float As[16 * 132];
  __shared__ float Bs[16 * 132];
  const int tid = threadIdx.x, bid = blockIdx.x;
  const int mt = bid % 150, nt = bid / 150;
  const int m0 = mt * 128, n0 = nt * 128;
  const int tx = tid & 15, ty = tid >> 4;
  const int mmS = tid & 127;
  const int gmS = m0 + mmS;
  const int bS = gmS / 600, tS = gmS % 600;
  const int kkS0 = tid >> 7;
  const int nnS0 = tid >> 4;
  const int kkSB = tid & 15;
  float acc[8][8];
  #pragma unroll
  for (int i = 0; i < 8; i++)
    #pragma unroll
    for (int jj = 0; jj < 8; jj++) acc[i][jj] = 0.f;
  for (int k0 = 0; k0 < 1024; k0 += 16) {
    #pragma unroll
    for (int r = 0; r < 8; r++) {
      int kk = kkS0 + 2 * r;
      As[kk * 132 + mmS] = P.enc2[(size_t)bS * 614400 + (size_t)(k0 + kk) * 600 + tS];
    }
    #pragma unroll
    for (int r = 0; r < 8; r++) {
      int nn = nnS0 + 16 * r;
      int n = n0 + nn;
      const float* src = (n < 512) ? (P.Wk + (size_t)n * 1024) : (P.Wv + (size_t)(n - 512) * 1024);
      Bs[kkSB * 132 + nn] = src[k0 + kkSB];
    }
    __syncthreads();
    #pragma unroll
    for (int kk = 0; kk < 16; kk++) {
      float4 A0 = *(const float4*)&As[kk * 132 + ty * 8];
      float4 A1 = *(const float4*)&As[kk * 132 + ty * 8 + 4];
      float4 B0 = *(const float4*)&Bs[kk * 132 + tx * 8];
      float4 B1 = *(const float4*)&Bs[kk * 132 + tx * 8 + 4];
      float av[8] = {A0.x, A0.y, A0.z, A0.w, A1.x, A1.y, A1.z, A1.w};
      float bw[8] = {B0.x, B0.y, B0.z, B0.w, B1.x, B1.y, B1.z, B1.w};
      #pragma unroll
      for (int i = 0; i < 8; i++)
        #pragma unroll
        for (int jj = 0; jj < 8; jj++) acc[i][jj] += av[i] * bw[jj];
    }
    __syncthreads();
  }
  #pragma unroll
  for (int i = 0; i < 8; i++) {
    int gm = m0 + ty * 8 + i;
    int b = gm / 600, t = gm % 600;
    #pragma unroll
    for (int jj = 0; jj < 8; jj++) {
      int n = n0 + tx * 8 + jj;
      float bia = (n < 512) ? P.bk[n] : P.bv[n - 512];
      float v = tanhf(acc[i][jj] + bia);
      if (n < 512) P.key_bt[(size_t)b * 307200 + (size_t)t * 512 + n] = v;
      else         P.val   [(size_t)b * 614400 + (size_t)t * 1024 + (n - 512)] = v;
    }
  }
}

// ---------------- persistent cooperative decoder (256 blocks x 256) ----------------
struct DecP {
  const float* Wq; const float* bq;
  const float* Wih_d; const float* Whh_d; const float* b_d;
  const float* Wc; const float* bc; const float* E;
  const int* flen;
  const float* key_bt; const float* val;
  float* h_d; float* c_d; float* last; float* q; float* ctx;
  float* scores; float* stats;
  float* out;
  u32* bar;
};

__global__ __launch_bounds__(256) void k_decoder(DecP P) {
  __shared__ float sm[16384];   // 64 KiB, reused per phase
  const int tid = threadIdx.x, bid = blockIdx.x;
  u32 epoch = 0;

  auto gsync = [&]() {
    __syncthreads();
    epoch++;
    const u32 target = 1000u + epoch;   // encoder used 1..600 on same slots
    if (tid == 0) {
      __threadfence();
      __hip_atomic_store(&P.bar[bid], target, __ATOMIC_RELEASE, __HIP_MEMORY_SCOPE_AGENT);
    }
    if (bid == (int)(epoch & 255u)) {
      if (tid < 64) {
        const int base = tid * 4;
        for (;;) {
          u32 a0 = __hip_atomic_load(&P.bar[base + 0], __ATOMIC_RELAXED, __HIP_MEMORY_SCOPE_AGENT);
          u32 a1 = __hip_atomic_load(&P.bar[base + 1], __ATOMIC_RELAXED, __HIP_MEMORY_SCOPE_AGENT);
          u32 a2 = __hip_atomic_load(&P.bar[base + 2], __ATOMIC_RELAXED, __HIP_MEMORY_SCOPE_AGENT);
          u32 a3 = __hip_atomic_load(&P.bar[base + 3], __ATOMIC_RELAXED, __HIP_MEMORY_SCOPE_AGENT);
          if (__all(umin4(a0, a1, a2, a3) >= target)) break;
          __builtin_amdgcn_s_sleep(1);
        }
        if (tid == 0) {
          __threadfence();
          __hip_atomic_store(&P.bar[256], target, __ATOMIC_RELEASE, __HIP_MEMORY_SCOPE_AGENT);
        }
      }
    }
    if (tid == 0) {
      while (__hip_atomic_load(&P.bar[256], __ATOMIC_ACQUIRE, __HIP_MEMORY_SCOPE_AGENT) < target)
        __builtin_amdgcn_s_sleep(2);
      __threadfence();
    }
    __syncthreads();
  };

  // P1: gates + cell update for step i
  auto phase_gates = [&](int i) {
    const int p = i & 1;
    const int bq4 = bid >> 6;
    const int jblk = bid & 63;
    const int b_lo = tid & 7;
    const int quad = (tid >> 3) & 3;
    const int j_lo = tid >> 5;
    const int bG = bq4 * 8 + b_lo;
    const int j = jblk * 8 + j_lo;
    const float* hsrc = P.h_d + p * 16384;
    for (int idx = tid; idx < 8 * 2048; idx += 256) {
      int bb = idx >> 11, c = idx & 2047;
      int gb = bq4 * 8 + bb;
      float v;
      if (c < 512)       v = P.last[gb * 512 + c];
      else if (c < 1536) v = P.ctx[gb * 1024 + (c - 512)];
      else               v = hsrc[gb * 512 + (c - 1536)];
      sm[bb * 2048 + (c ^ (bb << 2))] = v;
    }
    __syncthreads();
    const int k0 = quad << 9;
    const float* wbp; int rs, ko;
    if (quad < 3) { wbp = P.Wih_d; rs = 1536; ko = k0; }
    else          { wbp = P.Whh_d; rs = 512;  ko = 0;  }
    const float* r0 = wbp + (size_t)(j       ) * rs + ko;
    const float* r1 = wbp + (size_t)(512  + j) * rs + ko;
    const float* r2 = wbp + (size_t)(1024 + j) * rs + ko;
    const float* r3 = wbp + (size_t)(1536 + j) * rs + ko;
    const float* xb = sm + b_lo * 2048 + k0;
    const int xo = b_lo << 2;
    float a0 = 0.f, a1 = 0.f, a2 = 0.f, a3 = 0.f;
    #pragma unroll 4
    for (int k = 0; k < 512; k += 4) {
      float4 w0 = *(const float4*)(r0 + k);
      float4 w1 = *(const float4*)(r1 + k);
      float4 w2 = *(const float4*)(r2 + k);
      float4 w3 = *(const float4*)(r3 + k);
      float4 x  = *(const float4*)(xb + (k ^ xo));
      a0 += w0.x * x.x + w0.y * x.y + w0.z * x.z + w0.w * x.w;
      a1 += w1.x * x.x + w1.y * x.y + w1.z * x.z + w1.w * x.w;
      a2 += w2.x * x.x + w2.y * x.y + w2.z * x.z + w2.w * x.w;
      a3 += w3.x * x.x + w3.y * x.y + w3.z * x.z + w3.w * x.w;
    }
    a0 += __shfl_xor(a0, 8); a0 += __shfl_xor(a0, 16);
    a1 += __shfl_xor(a1, 8); a1 += __shfl_xor(a1, 16);
    a2 += __shfl_xor(a2, 8); a2 += __shfl_xor(a2, 16);
    a3 += __shfl_xor(a3, 8); a3 += __shfl_xor(a3, 16);
    if (quad == 0) {
      float gi = a0 + P.b_d[j];
      float gf = a1 + P.b_d[512 + j];
      float gg = a2 + P.b_d[1024 + j];
      float go = a3 + P.b_d[1536 + j];
      int ci = bG * 512 + j;
      float co = P.c_d[ci];
      float cn = sigf(gf) * co + sigf(gi) * tanhf(gg);
      float hn = sigf(go) * tanhf(cn);
      P.c_d[ci] = cn;
      P.h_d[(p ^ 1) * 16384 + ci] = hn;
    }
  };

  // P2: logits_i (every thread: 1 row-pair) + q_{i+1} (every 8th thread)
  auto phase_logits_q = [&](int i) {
    const int pn = (i & 1) ^ 1;
    const float* hsrc = P.h_d + pn * 16384;
    for (int idx = tid; idx < 16384; idx += 256) {
      int bb = idx >> 9, k = idx & 511;
      sm[bb * 512 + (k ^ ((bb & 7) << 2))] = hsrc[idx];
    }
    __syncthreads();
    if (i >= 0) {
      int pidx = bid * 256 + tid;          // 0..65535 exactly
      int bb = pidx & 31;
      int v0 = (pidx >> 5) << 1;
      const float* w0 = P.Wc + (size_t)v0 * 512;
      const float* w1 = w0 + 512;
      const float* hbp = sm + bb * 512;
      const int xo = (bb & 7) << 2;
      float s0 = 0.f, s1 = 0.f;
      #pragma unroll 4
      for (int k = 0; k < 512; k += 4) {
        float4 A0 = *(const float4*)(w0 + k);
        float4 A1 = *(const float4*)(w1 + k);
        int kx = k ^ xo;
        float h0 = hbp[kx], h1 = hbp[kx + 1], h2 = hbp[kx + 2], h3 = hbp[kx + 3];
        s0 += A0.x * h0 + A0.y * h1 + A0.z * h2 + A0.w * h3;
        s1 += A1.x * h0 + A1.y * h1 + A1.z * h2 + A1.w * h3;
      }
      size_t o = (size_t)bb * 491520 + (size_t)i * 4096 + v0;
      P.out[o]     = s0 + P.bc[v0];
      P.out[o + 1] = s1 + P.bc[v0 + 1];
    }
    if ((tid & 7) == 0) {
      int qp = bid * 32 + (tid >> 3);      // 0..8191
      int bb = qp & 31;
      int d0 = (qp >> 5) << 1;
      const float* w0 = P.Wq + (size_t)d0 * 512;
      const float* w1 = w0 + 512;
      const float* hbp = sm + bb * 512;
      const int xo = (bb & 7) << 2;
      float s0 = 0.f, s1 = 0.f;
      #pragma unroll 4
      for (int k = 0; k < 512; k += 4) {
        float4 A0 = *(const float4*)(w0 + k);
        float4 A1 = *(const float4*)(w1 + k);
        int kx = k ^ xo;
        float h0 = hbp[kx], h1 = hbp[kx + 1], h2 = hbp[kx + 2], h3 = hbp[kx + 3];
        s0 += A0.x * h0 + A0.y * h1 + A0.z * h2 + A0.w * h3;
        s1 += A1.x * h0 + A1.y * h1 + A1.z * h2 + A1.w * h3;
      }
      P.q[bb * 512 + d0]     = tanhf(s0 + P.bq[d0]);
      P.q[bb * 512 + d0 + 1] = tanhf(s1 + P.bq[d0 + 1]);
    }
  };

  // P3: argmax_i (blocks 0..31)  ||  scores_{i+1} chunks (blocks 32..223: 32 b x 6 chunks)
  auto phase_amax_scores = [&](int i, bool do_scores) {
    if (bid < 32) {
      if (i < 0) return;
      const float* row = P.out + (size_t)bid * 491520 + (size_t)i * 4096;
      float bv = -INFINITY; int bi = 0;
      for (int v = tid; v < 4096; v += 256) {
        float x = row[v];
        if (x > bv) { bv = x; bi = v; }
      }
      float* smax = sm;
      int* sidx = (int*)(sm + 256);
      smax[tid] = bv; sidx[tid] = bi;
      __syncthreads();
      for (int off = 128; off > 0; off >>= 1) {
        if (tid < off) {
          float ov = smax[tid + off]; int oi = sidx[tid + off];
          if (ov > smax[tid] || (ov == smax[tid] && oi < sidx[tid])) { smax[tid] = ov; sidx[tid] = oi; }
        }
        __syncthreads();
      }
      int widx = sidx[0];
      for (int k = tid; k < 512; k += 256) P.last[bid * 512 + k] = P.E[(size_t)widx * 512 + k];
    } else if (bid < 224) {
      if (!do_scores) return;
      const int sb = bid - 32;
      const int b = sb / 6, ch = sb - 6 * b;
      const int t0 = ch * 100;
      const int wv = tid >> 6, lane = tid & 63;
      const int kbase = lane * 8;
      const int len = P.flen[b];
      float qreg[8];
      {
        const float* qb = P.q + b * 512 + kbase;
        #pragma unroll
        for (int jj = 0; jj < 8; jj++) qreg[jj] = qb[jj];
      }
      const float* kb = P.key_bt + (size_t)b * 307200 + kbase;
      float mloc = -INFINITY;
      for (int it = 0; it < 25; ++it) {
        const int t = t0 + wv * 25 + it;
        const nt_f4* kr = (const nt_f4*)(kb + (size_t)t * 512);
        nt_f4 u0 = __builtin_nontemporal_load(kr);
        nt_f4 u1 = __builtin_nontemporal_load(kr + 1);
        float s = qreg[0] * u0.x + qreg[1] * u0.y + qreg[2] * u0.z + qreg[3] * u0.w
                + qreg[4] * u1.x + qreg[5] * u1.y + qreg[6] * u1.z + qreg[7] * u1.w;
        s += __shfl_xor(s, 1);  s += __shfl_xor(s, 2);  s += __shfl_xor(s, 4);
        s += __shfl_xor(s, 8);  s += __shfl_xor(s, 16); s += __shfl_xor(s, 32);
        float sc = (t < len) ? 2.0f * s : -1e30f;
        if (lane == 0) P.scores[b * 600 + t] = sc;
        mloc = fmaxf(mloc, sc);
      }
      if (lane == 0) sm[wv] = mloc;
      __syncthreads();
      if (tid == 0)
        P.stats[b * 8 + ch] = fmaxf(fmaxf(sm[0], sm[1]), fmaxf(sm[2], sm[3]));
    }
  };

  // P4: ctx for step att_i + att_seq writes (32 b x 8 w-chunks)
  auto phase_ctx = [&](int att_i) {
    const int b = bid >> 3, wblk = bid & 7;
    const float* st = P.stats + b * 8;
    float M = fmaxf(fmaxf(fmaxf(st[0], st[1]), fmaxf(st[2], st[3])), fmaxf(st[4], st[5]));
    float* pl = sm;              // [600]
    float* red = sm + 640;       // [256]
    float Lloc = 0.f;
    for (int t = tid; t < 600; t += 256) {
      float e = expf(P.scores[b * 600 + t] - M);
      pl[t] = e;
      Lloc += e;
    }
    red[tid] = Lloc;
    __syncthreads();
    for (int off = 128; off > 0; off >>= 1) {
      if (tid < off) red[tid] += red[tid + off];
      __syncthreads();
    }
    const float L = red[0];
    __syncthreads();
    const float invL = 1.0f / L;
    if (wblk == 0) {
      for (int t = tid; t < 600; t += 256)
        P.out[15728640ull + (size_t)b * 72000 + (size_t)att_i * 600 + t] = pl[t] * invL;
    }
    const int w = (wblk << 7) + (tid & 127);
    const int th = tid >> 7;
    const float* vb = P.val + (size_t)b * 614400 + w;
    float acc = 0.f;
    #pragma unroll 8
    for (int t = th * 300; t < th * 300 + 300; t++)
      acc += pl[t] * __builtin_nontemporal_load(vb + (size_t)t * 1024);
    red[tid] = acc;
    __syncthreads();
    if (tid < 128)
      P.ctx[b * 1024 + (wblk << 7) + tid] = (red[tid] + red[tid + 128]) * invL;
  };

  // ---- pipeline ----
  phase_logits_q(-1);            // q_0
  gsync();
  phase_amax_scores(-1, true);   // scores_0
  gsync();
  phase_ctx(0);                  // ctx_0, att_seq[:,0,:]
  gsync();
  for (int i = 0; i < 120; i++) {
    phase_gates(i);
    gsync();
    phase_logits_q(i);           // logits_i, q_{i+1}
    gsync();
    phase_amax_scores(i, i < 119);
    gsync();
    if (i < 119) phase_ctx(i + 1);
    gsync();
  }
}

// ---------------- launch ----------------
extern "C" void kernel_launch(void* const* d_in, const int* in_sizes, int n_in,
                              void* d_out, int out_size, void* d_ws, size_t ws_size,
                              hipStream_t stream) {
  const float* audio = (const float*)d_in[0];
  const float* Wih_f = (const float*)d_in[1];
  const float* Whh_f = (const float*)d_in[2];
  const float* b_f   = (const float*)d_in[3];
  const float* Wih_b = (const float*)d_in[4];
  const float* Whh_b = (const float*)d_in[5];
  const float* b_b   = (const float*)d_in[6];
  const float* Wq    = (const float*)d_in[7];
  const float* bq    = (const float*)d_in[8];
  const float* Wk    = (const float*)d_in[9];
  const float* bk    = (const float*)d_in[10];
  const float* Wv    = (const float*)d_in[11];
  const float* bv    = (const float*)d_in[12];
  const float* Wih_d = (const float*)d_in[13];
  const float* Whh_d = (const float*)d_in[14];
  const float* b_d   = (const float*)d_in[15];
  const float* Wc    = (const float*)d_in[16];
  const float* bc    = (const float*)d_in[17];
  const float* E     = (const float*)d_in[18];
  const int*   flen  = (const int*)d_in[19];
  float* out = (float*)d_out;
  char* ws = (char*)d_ws;

  u32*   bar     = (u32*)  (ws + OFF_BAR);
  float* h_enc   = (float*)(ws + OFF_HENC);
  float* c_enc   = (float*)(ws + OFF_CENC);
  float* h_d     = (float*)(ws + OFF_HD);
  float* c_d     = (float*)(ws + OFF_CD);
  float* last    = (float*)(ws + OFF_LAST);
  float* qbuf    = (float*)(ws + OFF_Q);
  float* ctx     = (float*)(ws + OFF_CTX);
  float* scores  = (float*)(ws + OFF_SCORES);
  float* stats   = (float*)(ws + OFF_STATS);
  float* audio_T = (float*)(ws + OFF_AUDIOT);
  float* enc2    = (float*)(ws + OFF_ENC2);
  float* key_bt  = (float*)(ws + OFF_KEYT);
  float* val     = (float*)(ws + OFF_VAL);

  (void)hipMemsetAsync(ws, 0, STATE_BYTES, stream);
  k_init_last<<<64, 256, 0, stream>>>(E, last);
  k_prep_audio<<<(T_ * FIN_ * 32 + 255) / 256, 256, 0, stream>>>(audio, audio_T);

  EncP ep{audio_T, Wih_f, Whh_f, b_f, Wih_b, Whh_b, b_b, h_enc, c_enc, enc2, bar};
  void* ea[] = { &ep };
  (void)hipLaunchCooperativeKernel((const void*)k_encoder, dim3(256), dim3(256), ea, 0, stream);

  KVP kp{enc2, Wk, bk, Wv, bv, key_bt, val};
  k_keyval<<<1800, 256, 0, stream>>>(kp);

  DecP dp{Wq, bq, Wih_d, Whh_d, b_d, Wc, bc, E, flen, key_bt, val,
          h_d, c_d, last, qbuf, ctx, scores, stats, out, bar};
  void* da[] = { &dp };
  (void)hipLaunchCooperativeKernel((const void*)k_decoder, dim3(256), dim3(256), da, 0, stream);
}

// Round 6
// 35498.923 us; speedup vs baseline: 2.1280x; 1.6416x over previous
//
#include <hip/hip_runtime.h>
#include <math.h>

typedef unsigned int u32;
typedef float nt_f4 __attribute__((ext_vector_type(4)));

#define T_    600
#define FIN_  120

// ---- ws byte offsets ----
#define OFF_BAR      0ull          // 2048 B: arrive[256] @0, dec_flag @bar[256], enc_flag[g] @bar[257+g]
#define OFF_HENC     2048ull       // [2 parity][2 dir][512][32] f32 = 262144
#define OFF_CENC     264192ull     // (unused; layout compat)
#define OFF_HD       395264ull     // [2 parity][32][512] = 131072
#define OFF_CD       526336ull     // [32][512] = 65536
#define STATE_BYTES  591872ull     // memset-0 region
#define OFF_LAST     591872ull     // [32][512]
#define OFF_Q        657408ull     // [32][512]
#define OFF_CTX      722944ull     // [32][1024]
#define OFF_SCORES   854016ull     // [32][600]
#define OFF_STATS    930816ull     // [32][8] chunk maxes (1024 B)
#define OFF_AUDIOT   931840ull     // [600][120][32]
#define OFF_ENC2     10147840ull   // [32][1024][600]
#define OFF_KEYT     88791040ull   // key_bt [32][600][512]
#define OFF_VAL      128112640ull  // val [32][600][1024]

__device__ __forceinline__ float sigf(float x) { return 1.0f / (1.0f + expf(-x)); }
__device__ __forceinline__ u32 umin4(u32 a, u32 b, u32 c, u32 d) {
  u32 x = a < b ? a : b; u32 y = c < d ? c : d; return x < y ? x : y;
}
// L3-coherent (sc0 sc1) scalar access — bypasses non-coherent L2, no fence needed.
__device__ __forceinline__ void st_sys(float* p, float v) {
  __hip_atomic_store(p, v, __ATOMIC_RELAXED, __HIP_MEMORY_SCOPE_AGENT);
}
__device__ __forceinline__ float ld_sys(const float* p) {
  return __hip_atomic_load(p, __ATOMIC_RELAXED, __HIP_MEMORY_SCOPE_AGENT);
}
#define VM_FENCE() asm volatile("s_waitcnt vmcnt(0)" ::: "memory")
#define C_FENCE()  asm volatile("" ::: "memory")

// ---------------- prep ----------------
__global__ __launch_bounds__(256) void k_prep_audio(const float* __restrict__ audio,
                                                    float* __restrict__ audio_T) {
  int idx = blockIdx.x * 256 + threadIdx.x;
  if (idx >= T_ * FIN_ * 32) return;
  int b = idx & 31;
  int r = idx >> 5;
  int f = r % FIN_;
  int t = r / FIN_;
  audio_T[idx] = audio[(size_t)b * (T_ * FIN_) + t * FIN_ + f];
}

__global__ __launch_bounds__(256) void k_init_last(const float* __restrict__ E,
                                                   float* __restrict__ last) {
  int idx = blockIdx.x * 256 + threadIdx.x;
  if (idx < 32 * 512) last[idx] = E[idx & 511];
}

// ---------------- persistent cooperative encoder (256 blocks x 256) ----------------
struct EncP {
  const float* audio_T;
  const float* Wih_f; const float* Whh_f; const float* b_f;
  const float* Wih_b; const float* Whh_b; const float* b_b;
  float* h_enc; float* c_enc; float* enc2;
  u32* bar;
};

__global__ __launch_bounds__(256) void k_encoder(EncP P) {
  __shared__ float hl[8192];          // [512 j][16 b]
  const int tid = threadIdx.x, bid = blockIdx.x;
  const int grp = bid >> 6;           // 0..3 : dir*2+bhalf
  const int dir = grp >> 1, bhalf = grp & 1;
  const int jblk = bid & 63;
  const int b_lo = tid & 15;
  const int half = (tid >> 4) & 1;
  const int j_lo = tid >> 5;          // 0..7
  const int j = jblk * 8 + j_lo;
  const int bG = bhalf * 16 + b_lo;
  const float* Wih  = dir ? P.Wih_b : P.Wih_f;
  const float* Whh  = dir ? P.Whh_b : P.Whh_f;
  const float* bias = dir ? P.b_b   : P.b_f;
  u32* arrive = P.bar + grp * 64;
  u32* flag   = P.bar + 257 + grp;

  const float* WihR0 = Wih + (size_t)(j       ) * 120 + half * 60;
  const float* WihR1 = Wih + (size_t)(512  + j) * 120 + half * 60;
  const float* WihR2 = Wih + (size_t)(1024 + j) * 120 + half * 60;
  const float* WihR3 = Wih + (size_t)(1536 + j) * 120 + half * 60;
  const float* WhhR0 = Whh + (size_t)(j       ) * 512 + half * 256;
  const float* WhhR1 = Whh + (size_t)(512  + j) * 512 + half * 256;
  const float* WhhR2 = Whh + (size_t)(1024 + j) * 512 + half * 256;
  const float* WhhR3 = Whh + (size_t)(1536 + j) * 512 + half * 256;
  const float bia0 = bias[j], bia1 = bias[512 + j], bia2 = bias[1024 + j], bia3 = bias[1536 + j];

  float creg = 0.f;

  for (int s = 0; s < 600; s++) {
    const int t = dir ? (599 - s) : s;
    const int p = s & 1;
    {
      const float* hsrc = P.h_enc + (size_t)(p * 2 + dir) * 16384 + bhalf * 16;
      for (int idx = tid; idx < 8192; idx += 256) {
        int jj = idx >> 4, bb = idx & 15;
        hl[jj * 16 + bb] = ld_sys(hsrc + jj * 32 + bb);
      }
    }
    __syncthreads();

    float a0 = 0.f, a1 = 0.f, a2 = 0.f, a3 = 0.f;
    {
      const float* xg = P.audio_T + (size_t)t * 3840 + half * 1920 + bG;
      for (int kl = 0; kl < 60; kl += 4) {
        float4 w0 = *(const float4*)(WihR0 + kl);
        float4 w1 = *(const float4*)(WihR1 + kl);
        float4 w2 = *(const float4*)(WihR2 + kl);
        float4 w3 = *(const float4*)(WihR3 + kl);
        float x0 = xg[(kl + 0) * 32], x1 = xg[(kl + 1) * 32];
        float x2 = xg[(kl + 2) * 32], x3 = xg[(kl + 3) * 32];
        a0 += w0.x * x0 + w0.y * x1 + w0.z * x2 + w0.w * x3;
        a1 += w1.x * x0 + w1.y * x1 + w1.z * x2 + w1.w * x3;
        a2 += w2.x * x0 + w2.y * x1 + w2.z * x2 + w2.w * x3;
        a3 += w3.x * x0 + w3.y * x1 + w3.z * x2 + w3.w * x3;
      }
    }
    {
      const float* hb = hl + half * 4096 + b_lo;
      #pragma unroll 4
      for (int kl = 0; kl < 256; kl += 4) {
        float4 w0 = *(const float4*)(WhhR0 + kl);
        float4 w1 = *(const float4*)(WhhR1 + kl);
        float4 w2 = *(const float4*)(WhhR2 + kl);
        float4 w3 = *(const float4*)(WhhR3 + kl);
        float x0 = hb[(kl + 0) * 16], x1 = hb[(kl + 1) * 16];
        float x2 = hb[(kl + 2) * 16], x3 = hb[(kl + 3) * 16];
        a0 += w0.x * x0 + w0.y * x1 + w0.z * x2 + w0.w * x3;
        a1 += w1.x * x0 + w1.y * x1 + w1.z * x2 + w1.w * x3;
        a2 += w2.x * x0 + w2.y * x1 + w2.z * x2 + w2.w * x3;
        a3 += w3.x * x0 + w3.y * x1 + w3.z * x2 + w3.w * x3;
      }
    }
    a0 += __shfl_xor(a0, 16);
    a1 += __shfl_xor(a1, 16);
    a2 += __shfl_xor(a2, 16);
    a3 += __shfl_xor(a3, 16);
    if (half == 0) {
      float gi = a0 + bia0, gf = a1 + bia1, gg = a2 + bia2, go = a3 + bia3;
      creg = sigf(gf) * creg + sigf(gi) * tanhf(gg);
      float hn = sigf(go) * tanhf(creg);
      st_sys(&P.h_enc[(size_t)((p ^ 1) * 2 + dir) * 16384 + j * 32 + bG], hn);
      P.enc2[(size_t)bG * 614400 + (size_t)(dir * 512 + j) * 600 + t] = hn;  // kernel-end flush
    }
    // ---- fence-free flag barrier over 64 blocks of this group ----
    VM_FENCE();                   // per-wave: all sc1 stores complete at L3
    __syncthreads();
    const u32 target = (u32)(s + 1);
    if (tid == 0)
      __hip_atomic_store(&arrive[jblk], target, __ATOMIC_RELAXED, __HIP_MEMORY_SCOPE_AGENT);
    if (jblk == (s & 63)) {
      if (tid < 16) {
        const int base = tid * 4;
        for (;;) {
          u32 a0_ = __hip_atomic_load(&arrive[base + 0], __ATOMIC_RELAXED, __HIP_MEMORY_SCOPE_AGENT);
          u32 a1_ = __hip_atomic_load(&arrive[base + 1], __ATOMIC_RELAXED, __HIP_MEMORY_SCOPE_AGENT);
          u32 a2_ = __hip_atomic_load(&arrive[base + 2], __ATOMIC_RELAXED, __HIP_MEMORY_SCOPE_AGENT);
          u32 a3_ = __hip_atomic_load(&arrive[base + 3], __ATOMIC_RELAXED, __HIP_MEMORY_SCOPE_AGENT);
          if (__all(umin4(a0_, a1_, a2_, a3_) >= target)) break;
          __builtin_amdgcn_s_sleep(1);
        }
        if (tid == 0)
          __hip_atomic_store(flag, target, __ATOMIC_RELAXED, __HIP_MEMORY_SCOPE_AGENT);
      }
    }
    if (tid == 0) {
      while (__hip_atomic_load(flag, __ATOMIC_RELAXED, __HIP_MEMORY_SCOPE_AGENT) < target)
        __builtin_amdgcn_s_sleep(2);
    }
    C_FENCE();
    __syncthreads();
  }
}

// ---------------- key/val GEMM: key -> [b][t][k], val -> [b][t][w] ----------------
struct KVP {
  const float* enc2; const float* Wk; const float* bk; const float* Wv; const float* bv;
  float* key_bt; float* val;
};

__global__ __launch_bounds__(256) void k_keyval(KVP P) {
  __shared__ float As[16 * 132];
  __shared__ float Bs[16 * 132];
  const int tid = threadIdx.x, bid = blockIdx.x;
  const int mt = bid % 150, nt = bid / 150;
  const int m0 = mt * 128, n0 = nt * 128;
  const int tx = tid & 15, ty = tid >> 4;
  const int mmS = tid & 127;
  const int gmS = m0 + mmS;
  const int bS = gmS / 600, tS = gmS % 600;
  const int kkS0 = tid >> 7;
  const int nnS0 = tid >> 4;
  const int kkSB = tid & 15;
  float acc[8][8];
  #pragma unroll
  for (int i = 0; i < 8; i++)
    #pragma unroll
    for (int jj = 0; jj < 8; jj++) acc[i][jj] = 0.f;
  for (int k0 = 0; k0 < 1024; k0 += 16) {
    #pragma unroll
    for (int r = 0; r < 8; r++) {
      int kk = kkS0 + 2 * r;
      As[kk * 132 + mmS] = P.enc2[(size_t)bS * 614400 + (size_t)(k0 + kk) * 600 + tS];
    }
    #pragma unroll
    for (int r = 0; r < 8; r++) {
      int nn = nnS0 + 16 * r;
      int n = n0 + nn;
      const float* src = (n < 512) ? (P.Wk + (size_t)n * 1024) : (P.Wv + (size_t)(n - 512) * 1024);
      Bs[kkSB * 132 + nn] = src[k0 + kkSB];
    }
    __syncthreads();
    #pragma unroll
    for (int kk = 0; kk < 16; kk++) {
      float4 A0 = *(const float4*)&As[kk * 132 + ty * 8];
      float4 A1 = *(const float4*)&As[kk * 132 + ty * 8 + 4];
      float4 B0 = *(const float4*)&Bs[kk * 132 + tx * 8];
      float4 B1 = *(const float4*)&Bs[kk * 132 + tx * 8 + 4];
      float av[8] = {A0.x, A0.y, A0.z, A0.w, A1.x, A1.y, A1.z, A1.w};
      float bw[8] = {B0.x, B0.y, B0.z, B0.w, B1.x, B1.y, B1.z, B1.w};
      #pragma unroll
      for (int i = 0; i < 8; i++)
        #pragma unroll
        for (int jj = 0; jj < 8; jj++) acc[i][jj] += av[i] * bw[jj];
    }
    __syncthreads();
  }
  #pragma unroll
  for (int i = 0; i < 8; i++) {
    int gm = m0 + ty * 8 + i;
    int b = gm / 600, t = gm % 600;
    #pragma unroll
    for (int jj = 0; jj < 8; jj++) {
      int n = n0 + tx * 8 + jj;
      float bia = (n < 512) ? P.bk[n] : P.bv[n - 512];
      float v = tanhf(acc[i][jj] + bia);
      if (n < 512) P.key_bt[(size_t)b * 307200 + (size_t)t * 512 + n] = v;
      else         P.val   [(size_t)b * 614400 + (size_t)t * 1024 + (n - 512)] = v;
    }
  }
}

// ---------------- persistent cooperative decoder (256 blocks x 256) ----------------
struct DecP {
  const float* Wq; const float* bq;
  const float* Wih_d; const float* Whh_d; const float* b_d;
  const float* Wc; const float* bc; const float* E;
  const int* flen;
  const float* key_bt; const float* val;
  float* h_d; float* c_d; float* last; float* q; float* ctx;
  float* scores; float* stats;
  float* out;
  u32* bar;
};

__global__ __launch_bounds__(256) void k_decoder(DecP P) {
  __shared__ float sm[16384];   // 64 KiB, reused per phase
  const int tid = threadIdx.x, bid = blockIdx.x;
  u32 epoch = 0;

  auto gsync = [&]() {
    VM_FENCE();                 // per-wave: all sc1 stores complete at L3
    __syncthreads();
    epoch++;
    const u32 target = 1000u + epoch;   // encoder used 1..600 on same slots
    if (tid == 0)
      __hip_atomic_store(&P.bar[bid], target, __ATOMIC_RELAXED, __HIP_MEMORY_SCOPE_AGENT);
    if (bid == (int)(epoch & 255u)) {
      if (tid < 64) {
        const int base = tid * 4;
        for (;;) {
          u32 a0 = __hip_atomic_load(&P.bar[base + 0], __ATOMIC_RELAXED, __HIP_MEMORY_SCOPE_AGENT);
          u32 a1 = __hip_atomic_load(&P.bar[base + 1], __ATOMIC_RELAXED, __HIP_MEMORY_SCOPE_AGENT);
          u32 a2 = __hip_atomic_load(&P.bar[base + 2], __ATOMIC_RELAXED, __HIP_MEMORY_SCOPE_AGENT);
          u32 a3 = __hip_atomic_load(&P.bar[base + 3], __ATOMIC_RELAXED, __HIP_MEMORY_SCOPE_AGENT);
          if (__all(umin4(a0, a1, a2, a3) >= target)) break;
          __builtin_amdgcn_s_sleep(1);
        }
        if (tid == 0)
          __hip_atomic_store(&P.bar[256], target, __ATOMIC_RELAXED, __HIP_MEMORY_SCOPE_AGENT);
      }
    }
    if (tid == 0) {
      while (__hip_atomic_load(&P.bar[256], __ATOMIC_RELAXED, __HIP_MEMORY_SCOPE_AGENT) < target)
        __builtin_amdgcn_s_sleep(2);
    }
    C_FENCE();
    __syncthreads();
  };

  // P1: gates + cell update for step i
  auto phase_gates = [&](int i) {
    const int p = i & 1;
    const int bq4 = bid >> 6;
    const int jblk = bid & 63;
    const int b_lo = tid & 7;
    const int quad = (tid >> 3) & 3;
    const int j_lo = tid >> 5;
    const int bG = bq4 * 8 + b_lo;
    const int j = jblk * 8 + j_lo;
    const float* hsrc = P.h_d + p * 16384;
    for (int idx = tid; idx < 8 * 2048; idx += 256) {
      int bb = idx >> 11, c = idx & 2047;
      int gb = bq4 * 8 + bb;
      float v;
      if (c < 512)       v = ld_sys(&P.last[gb * 512 + c]);
      else if (c < 1536) v = ld_sys(&P.ctx[gb * 1024 + (c - 512)]);
      else               v = ld_sys(&hsrc[gb * 512 + (c - 1536)]);
      sm[bb * 2048 + (c ^ (bb << 2))] = v;
    }
    __syncthreads();
    const int k0 = quad << 9;
    const float* wbp; int rs, ko;
    if (quad < 3) { wbp = P.Wih_d; rs = 1536; ko = k0; }
    else          { wbp = P.Whh_d; rs = 512;  ko = 0;  }
    const float* r0 = wbp + (size_t)(j       ) * rs + ko;
    const float* r1 = wbp + (size_t)(512  + j) * rs + ko;
    const float* r2 = wbp + (size_t)(1024 + j) * rs + ko;
    const float* r3 = wbp + (size_t)(1536 + j) * rs + ko;
    const float* xb = sm + b_lo * 2048 + k0;
    const int xo = b_lo << 2;
    float a0 = 0.f, a1 = 0.f, a2 = 0.f, a3 = 0.f;
    #pragma unroll 4
    for (int k = 0; k < 512; k += 4) {
      float4 w0 = *(const float4*)(r0 + k);
      float4 w1 = *(const float4*)(r1 + k);
      float4 w2 = *(const float4*)(r2 + k);
      float4 w3 = *(const float4*)(r3 + k);
      float4 x  = *(const float4*)(xb + (k ^ xo));
      a0 += w0.x * x.x + w0.y * x.y + w0.z * x.z + w0.w * x.w;
      a1 += w1.x * x.x + w1.y * x.y + w1.z * x.z + w1.w * x.w;
      a2 += w2.x * x.x + w2.y * x.y + w2.z * x.z + w2.w * x.w;
      a3 += w3.x * x.x + w3.y * x.y + w3.z * x.z + w3.w * x.w;
    }
    a0 += __shfl_xor(a0, 8); a0 += __shfl_xor(a0, 16);
    a1 += __shfl_xor(a1, 8); a1 += __shfl_xor(a1, 16);
    a2 += __shfl_xor(a2, 8); a2 += __shfl_xor(a2, 16);
    a3 += __shfl_xor(a3, 8); a3 += __shfl_xor(a3, 16);
    if (quad == 0) {
      float gi = a0 + P.b_d[j];
      float gf = a1 + P.b_d[512 + j];
      float gg = a2 + P.b_d[1024 + j];
      float go = a3 + P.b_d[1536 + j];
      int ci = bG * 512 + j;
      float co = P.c_d[ci];                      // block-private: normal
      float cn = sigf(gf) * co + sigf(gi) * tanhf(gg);
      float hn = sigf(go) * tanhf(cn);
      P.c_d[ci] = cn;
      st_sys(&P.h_d[(p ^ 1) * 16384 + ci], hn);
    }
  };

  // P2: logits_i (every thread: 1 row-pair) + q_{i+1} (every 8th thread)
  auto phase_logits_q = [&](int i) {
    const int pn = (i & 1) ^ 1;
    const float* hsrc = P.h_d + pn * 16384;
    for (int idx = tid; idx < 16384; idx += 256) {
      int bb = idx >> 9, k = idx & 511;
      sm[bb * 512 + (k ^ ((bb & 7) << 2))] = ld_sys(&hsrc[idx]);
    }
    __syncthreads();
    if (i >= 0) {
      int pidx = bid * 256 + tid;          // 0..65535 exactly
      int bb = pidx & 31;
      int v0 = (pidx >> 5) << 1;
      const float* w0 = P.Wc + (size_t)v0 * 512;
      const float* w1 = w0 + 512;
      const float* hbp = sm + bb * 512;
      const int xo = (bb & 7) << 2;
      float s0 = 0.f, s1 = 0.f;
      #pragma unroll 4
      for (int k = 0; k < 512; k += 4) {
        float4 A0 = *(const float4*)(w0 + k);
        float4 A1 = *(const float4*)(w1 + k);
        int kx = k ^ xo;
        float h0 = hbp[kx], h1 = hbp[kx + 1], h2 = hbp[kx + 2], h3 = hbp[kx + 3];
        s0 += A0.x * h0 + A0.y * h1 + A0.z * h2 + A0.w * h3;
        s1 += A1.x * h0 + A1.y * h1 + A1.z * h2 + A1.w * h3;
      }
      size_t o = (size_t)bb * 491520 + (size_t)i * 4096 + v0;
      st_sys(&P.out[o],     s0 + P.bc[v0]);
      st_sys(&P.out[o + 1], s1 + P.bc[v0 + 1]);
    }
    if ((tid & 7) == 0) {
      int qp = bid * 32 + (tid >> 3);      // 0..8191
      int bb = qp & 31;
      int d0 = (qp >> 5) << 1;
      const float* w0 = P.Wq + (size_t)d0 * 512;
      const float* w1 = w0 + 512;
      const float* hbp = sm + bb * 512;
      const int xo = (bb & 7) << 2;
      float s0 = 0.f, s1 = 0.f;
      #pragma unroll 4
      for (int k = 0; k < 512; k += 4) {
        float4 A0 = *(const float4*)(w0 + k);
        float4 A1 = *(const float4*)(w1 + k);
        int kx = k ^ xo;
        float h0 = hbp[kx], h1 = hbp[kx + 1], h2 = hbp[kx + 2], h3 = hbp[kx + 3];
        s0 += A0.x * h0 + A0.y * h1 + A0.z * h2 + A0.w * h3;
        s1 += A1.x * h0 + A1.y * h1 + A1.z * h2 + A1.w * h3;
      }
      st_sys(&P.q[bb * 512 + d0],     tanhf(s0 + P.bq[d0]));
      st_sys(&P.q[bb * 512 + d0 + 1], tanhf(s1 + P.bq[d0 + 1]));
    }
  };

  // P3: argmax_i (blocks 0..31)  ||  scores_{i+1} chunks (blocks 32..223: 32 b x 6 chunks)
  auto phase_amax_scores = [&](int i, bool do_scores) {
    if (bid < 32) {
      if (i < 0) return;
      const float* row = P.out + (size_t)bid * 491520 + (size_t)i * 4096;
      float bv = -INFINITY; int bi = 0;
      for (int v = tid; v < 4096; v += 256) {
        float x = ld_sys(&row[v]);
        if (x > bv) { bv = x; bi = v; }
      }
      float* smax = sm;
      int* sidx = (int*)(sm + 256);
      smax[tid] = bv; sidx[tid] = bi;
      __syncthreads();
      for (int off = 128; off > 0; off >>= 1) {
        if (tid < off) {
          float ov = smax[tid + off]; int oi = sidx[tid + off];
          if (ov > smax[tid] || (ov == smax[tid] && oi < sidx[tid])) { smax[tid] = ov; sidx[tid] = oi; }
        }
        __syncthreads();
      }
      int widx = sidx[0];
      for (int k = tid; k < 512; k += 256)
        st_sys(&P.last[bid * 512 + k], P.E[(size_t)widx * 512 + k]);
    } else if (bid < 224) {
      if (!do_scores) return;
      const int sb = bid - 32;
      const int b = sb / 6, ch = sb - 6 * b;
      const int t0 = ch * 100;
      const int wv = tid >> 6, lane = tid & 63;
      const int kbase = lane * 8;
      const int len = P.flen[b];
      float qreg[8];
      {
        const float* qb = P.q + b * 512 + kbase;
        #pragma unroll
        for (int jj = 0; jj < 8; jj++) qreg[jj] = ld_sys(&qb[jj]);
      }
      const float* kb = P.key_bt + (size_t)b * 307200 + kbase;
      float mloc = -INFINITY;
      for (int it = 0; it < 25; ++it) {
        const int t = t0 + wv * 25 + it;
        const nt_f4* kr = (const nt_f4*)(kb + (size_t)t * 512);
        nt_f4 u0 = __builtin_nontemporal_load(kr);
        nt_f4 u1 = __builtin_nontemporal_load(kr + 1);
        float s = qreg[0] * u0.x + qreg[1] * u0.y + qreg[2] * u0.z + qreg[3] * u0.w
                + qreg[4] * u1.x + qreg[5] * u1.y + qreg[6] * u1.z + qreg[7] * u1.w;
        s += __shfl_xor(s, 1);  s += __shfl_xor(s, 2);  s += __shfl_xor(s, 4);
        s += __shfl_xor(s, 8);  s += __shfl_xor(s, 16); s += __shfl_xor(s, 32);
        float sc = (t < len) ? 2.0f * s : -1e30f;
        if (lane == 0) st_sys(&P.scores[b * 600 + t], sc);
        mloc = fmaxf(mloc, sc);
      }
      if (lane == 0) sm[wv] = mloc;
      __syncthreads();
      if (tid == 0)
        st_sys(&P.stats[b * 8 + ch], fmaxf(fmaxf(sm[0], sm[1]), fmaxf(sm[2], sm[3])));
    }
  };

  // P4: ctx for step att_i + att_seq writes (32 b x 8 w-chunks)
  auto phase_ctx = [&](int att_i) {
    const int b = bid >> 3, wblk = bid & 7;
    const float* st = P.stats + b * 8;
    float M = fmaxf(fmaxf(fmaxf(ld_sys(&st[0]), ld_sys(&st[1])), fmaxf(ld_sys(&st[2]), ld_sys(&st[3]))),
                    fmaxf(ld_sys(&st[4]), ld_sys(&st[5])));
    float* pl = sm;              // [600]
    float* red = sm + 640;       // [256]
    float Lloc = 0.f;
    for (int t = tid; t < 600; t += 256) {
      float e = expf(ld_sys(&P.scores[b * 600 + t]) - M);
      pl[t] = e;
      Lloc += e;
    }
    red[tid] = Lloc;
    __syncthreads();
    for (int off = 128; off > 0; off >>= 1) {
      if (tid < off) red[tid] += red[tid + off];
      __syncthreads();
    }
    const float L = red[0];
    __syncthreads();
    const float invL = 1.0f / L;
    if (wblk == 0) {
      for (int t = tid; t < 600; t += 256)
        P.out[15728640ull + (size_t)b * 72000 + (size_t)att_i * 600 + t] = pl[t] * invL;  // harness-only
    }
    const int w = (wblk << 7) + (tid & 127);
    const int th = tid >> 7;
    const float* vb = P.val + (size_t)b * 614400 + w;
    float acc = 0.f;
    #pragma unroll 8
    for (int t = th * 300; t < th * 300 + 300; t++)
      acc += pl[t] * __builtin_nontemporal_load(vb + (size_t)t * 1024);
    red[tid] = acc;
    __syncthreads();
    if (tid < 128)
      st_sys(&P.ctx[b * 1024 + (wblk << 7) + tid], (red[tid] + red[tid + 128]) * invL);
  };

  // ---- pipeline ----
  phase_logits_q(-1);            // q_0
  gsync();
  phase_amax_scores(-1, true);   // scores_0
  gsync();
  phase_ctx(0);                  // ctx_0, att_seq[:,0,:]
  gsync();
  for (int i = 0; i < 120; i++) {
    phase_gates(i);
    gsync();
    phase_logits_q(i);           // logits_i, q_{i+1}
    gsync();
    phase_amax_scores(i, i < 119);
    gsync();
    if (i < 119) phase_ctx(i + 1);
    gsync();
  }
}

// ---------------- launch ----------------
extern "C" void kernel_launch(void* const* d_in, const int* in_sizes, int n_in,
                              void* d_out, int out_size, void* d_ws, size_t ws_size,
                              hipStream_t stream) {
  const float* audio = (const float*)d_in[0];
  const float* Wih_f = (const float*)d_in[1];
  const float* Whh_f = (const float*)d_in[2];
  const float* b_f   = (const float*)d_in[3];
  const float* Wih_b = (const float*)d_in[4];
  const float* Whh_b = (const float*)d_in[5];
  const float* b_b   = (const float*)d_in[6];
  const float* Wq    = (const float*)d_in[7];
  const float* bq    = (const float*)d_in[8];
  const float* Wk    = (const float*)d_in[9];
  const float* bk    = (const float*)d_in[10];
  const float* Wv    = (const float*)d_in[11];
  const float* bv    = (const float*)d_in[12];
  const float* Wih_d = (const float*)d_in[13];
  const float* Whh_d = (const float*)d_in[14];
  const float* b_d   = (const float*)d_in[15];
  const float* Wc    = (const float*)d_in[16];
  const float* bc    = (const float*)d_in[17];
  const float* E     = (const float*)d_in[18];
  const int*   flen  = (const int*)d_in[19];
  float* out = (float*)d_out;
  char* ws = (char*)d_ws;

  u32*   bar     = (u32*)  (ws + OFF_BAR);
  float* h_enc   = (float*)(ws + OFF_HENC);
  float* c_enc   = (float*)(ws + OFF_CENC);
  float* h_d     = (float*)(ws + OFF_HD);
  float* c_d     = (float*)(ws + OFF_CD);
  float* last    = (float*)(ws + OFF_LAST);
  float* qbuf    = (float*)(ws + OFF_Q);
  float* ctx     = (float*)(ws + OFF_CTX);
  float* scores  = (float*)(ws + OFF_SCORES);
  float* stats   = (float*)(ws + OFF_STATS);
  float* audio_T = (float*)(ws + OFF_AUDIOT);
  float* enc2    = (float*)(ws + OFF_ENC2);
  float* key_bt  = (float*)(ws + OFF_KEYT);
  float* val     = (float*)(ws + OFF_VAL);

  (void)hipMemsetAsync(ws, 0, STATE_BYTES, stream);
  k_init_last<<<64, 256, 0, stream>>>(E, last);
  k_prep_audio<<<(T_ * FIN_ * 32 + 255) / 256, 256, 0, stream>>>(audio, audio_T);

  EncP ep{audio_T, Wih_f, Whh_f, b_f, Wih_b, Whh_b, b_b, h_enc, c_enc, enc2, bar};
  void* ea[] = { &ep };
  (void)hipLaunchCooperativeKernel((const void*)k_encoder, dim3(256), dim3(256), ea, 0, stream);

  KVP kp{enc2, Wk, bk, Wv, bv, key_bt, val};
  k_keyval<<<1800, 256, 0, stream>>>(kp);

  DecP dp{Wq, bq, Wih_d, Whh_d, b_d, Wc, bc, E, flen, key_bt, val,
          h_d, c_d, last, qbuf, ctx, scores, stats, out, bar};
  void* da[] = { &dp };
  (void)hipLaunchCooperativeKernel((const void*)k_decoder, dim3(256), dim3(256), da, 0, stream);
}

// Round 7
// 21945.477 us; speedup vs baseline: 3.4423x; 1.6176x over previous
//
#include <hip/hip_runtime.h>
#include <math.h>

typedef unsigned int u32;

#define T_    600
#define FIN_  120

// ---- ws byte offsets ----
#define OFF_BAR      0ull          // 2048 B: arrive[256] @0, dec_flag @bar[256], enc_flag[g] @bar[257+g]
#define OFF_HENC     2048ull       // [2 parity][2 dir][512][32] f32 = 262144
#define OFF_CENC     264192ull     // (unused; layout compat)
#define OFF_HD       395264ull     // [2 parity][32][512] = 131072
#define OFF_CD       526336ull     // [32][512] = 65536
#define STATE_BYTES  591872ull     // memset-0 region
#define OFF_LAST     591872ull     // [32][512]
#define OFF_Q        657408ull     // [32][512]
#define OFF_CTX      722944ull     // [32][1024]
#define OFF_SCORES   854016ull     // [32][600]
#define OFF_STATS    930816ull     // [32][8] chunk maxes (1024 B)
#define OFF_AUDIOT   931840ull     // [600][120][32]
#define OFF_ENC2     10147840ull   // [32][1024][600]
#define OFF_KEYT     88791040ull   // key_bt [32][600][512]
#define OFF_VAL      128112640ull  // val [32][600][1024]

__device__ __forceinline__ float sigf(float x) { return 1.0f / (1.0f + expf(-x)); }
__device__ __forceinline__ u32 umin4(u32 a, u32 b, u32 c, u32 d) {
  u32 x = a < b ? a : b; u32 y = c < d ? c : d; return x < y ? x : y;
}
// L3-coherent scalar access — bypasses non-coherent L2, no cache-nuking fence needed.
__device__ __forceinline__ void st_sys(float* p, float v) {
  __hip_atomic_store(p, v, __ATOMIC_RELAXED, __HIP_MEMORY_SCOPE_AGENT);
}
__device__ __forceinline__ float ld_sys(const float* p) {
  return __hip_atomic_load(p, __ATOMIC_RELAXED, __HIP_MEMORY_SCOPE_AGENT);
}
#define VM_FENCE() asm volatile("s_waitcnt vmcnt(0)" ::: "memory")
#define C_FENCE()  asm volatile("" ::: "memory")

// ---------------- prep ----------------
__global__ __launch_bounds__(256) void k_prep_audio(const float* __restrict__ audio,
                                                    float* __restrict__ audio_T) {
  int idx = blockIdx.x * 256 + threadIdx.x;
  if (idx >= T_ * FIN_ * 32) return;
  int b = idx & 31;
  int r = idx >> 5;
  int f = r % FIN_;
  int t = r / FIN_;
  audio_T[idx] = audio[(size_t)b * (T_ * FIN_) + t * FIN_ + f];
}

__global__ __launch_bounds__(256) void k_init_last(const float* __restrict__ E,
                                                   float* __restrict__ last) {
  int idx = blockIdx.x * 256 + threadIdx.x;
  if (idx < 32 * 512) last[idx] = E[idx & 511];
}

// ---------------- persistent cooperative encoder (256 blocks x 512) ----------------
struct EncP {
  const float* audio_T;
  const float* Wih_f; const float* Whh_f; const float* b_f;
  const float* Wih_b; const float* Whh_b; const float* b_b;
  float* h_enc; float* c_enc; float* enc2;
  u32* bar;
};

__global__ __launch_bounds__(512) void k_encoder(EncP P) {
  __shared__ float hl[8192];          // [512 j][16 b]  32 KB
  __shared__ float hsave[4096];       // [128 r][32 t-slot] swizzled, 16 KB write-combine
  const int tid = threadIdx.x, bid = blockIdx.x;
  const int grp = bid >> 6;           // 0..3 : dir*2+bhalf
  const int dir = grp >> 1, bhalf = grp & 1;
  const int jblk = bid & 63;
  const int b_lo = tid & 15;
  const int kq = (tid >> 4) & 3;      // k-quarter
  const int j_lo = tid >> 6;          // 0..7 (wave index)
  const int j = jblk * 8 + j_lo;
  const int bG = bhalf * 16 + b_lo;
  const float* Wih  = dir ? P.Wih_b : P.Wih_f;
  const float* Whh  = dir ? P.Whh_b : P.Whh_f;
  const float* bias = dir ? P.b_b   : P.b_f;
  u32* arrive = P.bar + grp * 64;
  u32* flag   = P.bar + 257 + grp;

  const float* WihR0 = Wih + (size_t)(j       ) * 120 + kq * 30;
  const float* WihR1 = Wih + (size_t)(512  + j) * 120 + kq * 30;
  const float* WihR2 = Wih + (size_t)(1024 + j) * 120 + kq * 30;
  const float* WihR3 = Wih + (size_t)(1536 + j) * 120 + kq * 30;
  const float* WhhR0 = Whh + (size_t)(j       ) * 512 + kq * 128;
  const float* WhhR1 = Whh + (size_t)(512  + j) * 512 + kq * 128;
  const float* WhhR2 = Whh + (size_t)(1024 + j) * 512 + kq * 128;
  const float* WhhR3 = Whh + (size_t)(1536 + j) * 512 + kq * 128;
  const float bia0 = bias[j], bia1 = bias[512 + j], bia2 = bias[1024 + j], bia3 = bias[1536 + j];

  float creg = 0.f;                   // cell state, owned by kq==0 lanes

  for (int s = 0; s < 600; s++) {
    const int t = dir ? (599 - s) : s;
    const int p = s & 1;
    {
      const float* hsrc = P.h_enc + (size_t)(p * 2 + dir) * 16384 + bhalf * 16;
      for (int idx = tid; idx < 8192; idx += 512) {
        int jj = idx >> 4, bb = idx & 15;
        hl[jj * 16 + bb] = ld_sys(hsrc + jj * 32 + bb);
      }
    }
    __syncthreads();

    float a0 = 0.f, a1 = 0.f, a2 = 0.f, a3 = 0.f;
    // x part: 30 k per quarter (float2)
    {
      const float* xg = P.audio_T + (size_t)t * 3840 + (kq * 30) * 32 + bG;
      for (int kl = 0; kl < 30; kl += 2) {
        float2 w0 = *(const float2*)(WihR0 + kl);
        float2 w1 = *(const float2*)(WihR1 + kl);
        float2 w2 = *(const float2*)(WihR2 + kl);
        float2 w3 = *(const float2*)(WihR3 + kl);
        float x0 = xg[(kl + 0) * 32], x1 = xg[(kl + 1) * 32];
        a0 += w0.x * x0 + w0.y * x1;
        a1 += w1.x * x0 + w1.y * x1;
        a2 += w2.x * x0 + w2.y * x1;
        a3 += w3.x * x0 + w3.y * x1;
      }
    }
    // h part: 128 k per quarter
    {
      const float* hb = hl + (kq * 128) * 16 + b_lo;
      #pragma unroll 4
      for (int kl = 0; kl < 128; kl += 4) {
        float4 w0 = *(const float4*)(WhhR0 + kl);
        float4 w1 = *(const float4*)(WhhR1 + kl);
        float4 w2 = *(const float4*)(WhhR2 + kl);
        float4 w3 = *(const float4*)(WhhR3 + kl);
        float x0 = hb[(kl + 0) * 16], x1 = hb[(kl + 1) * 16];
        float x2 = hb[(kl + 2) * 16], x3 = hb[(kl + 3) * 16];
        a0 += w0.x * x0 + w0.y * x1 + w0.z * x2 + w0.w * x3;
        a1 += w1.x * x0 + w1.y * x1 + w1.z * x2 + w1.w * x3;
        a2 += w2.x * x0 + w2.y * x1 + w2.z * x2 + w2.w * x3;
        a3 += w3.x * x0 + w3.y * x1 + w3.z * x2 + w3.w * x3;
      }
    }
    a0 += __shfl_xor(a0, 16); a0 += __shfl_xor(a0, 32);
    a1 += __shfl_xor(a1, 16); a1 += __shfl_xor(a1, 32);
    a2 += __shfl_xor(a2, 16); a2 += __shfl_xor(a2, 32);
    a3 += __shfl_xor(a3, 16); a3 += __shfl_xor(a3, 32);
    if (kq == 0) {
      float gi = a0 + bia0, gf = a1 + bia1, gg = a2 + bia2, go = a3 + bia3;
      creg = sigf(gf) * creg + sigf(gi) * tanhf(gg);
      float hn = sigf(go) * tanhf(creg);
      st_sys(&P.h_enc[(size_t)((p ^ 1) * 2 + dir) * 16384 + j * 32 + bG], hn);
      int r = j_lo * 16 + b_lo;
      hsave[r * 32 + ((t + r) & 31)] = hn;      // write-combine buffer
    }
    // ---- barrier + deferred enc2 flush ----
    VM_FENCE();
    __syncthreads();
    const u32 target = (u32)(s + 1);
    if (tid == 0)
      __hip_atomic_store(&arrive[jblk], target, __ATOMIC_RELAXED, __HIP_MEMORY_SCOPE_AGENT);
    // flush a completed 32-t chunk (overlaps barrier wait)
    {
      bool doflush; int tbase;
      if (dir == 0) { doflush = ((t & 31) == 31) || (t == 599); tbase = (t == 599) ? 576 : (t - 31); }
      else          { doflush = ((t & 31) == 0);                 tbase = t; }
      if (doflush) {
        const int fmaxv = 599 - tbase;   // inclusive bound on f
        for (int idx = tid; idx < 4096; idx += 512) {
          int r = idx >> 5, f = idx & 31;
          if (f <= fmaxv) {
            float v = hsave[r * 32 + ((tbase + f + r) & 31)];
            int jl = r >> 4, bl = r & 15;
            P.enc2[(size_t)(bhalf * 16 + bl) * 614400 +
                   (size_t)(dir * 512 + jblk * 8 + jl) * 600 + tbase + f] = v;
          }
        }
      }
    }
    if (jblk == (s & 63)) {
      if (tid < 16) {
        const int base = tid * 4;
        for (;;) {
          u32 a0_ = __hip_atomic_load(&arrive[base + 0], __ATOMIC_RELAXED, __HIP_MEMORY_SCOPE_AGENT);
          u32 a1_ = __hip_atomic_load(&arrive[base + 1], __ATOMIC_RELAXED, __HIP_MEMORY_SCOPE_AGENT);
          u32 a2_ = __hip_atomic_load(&arrive[base + 2], __ATOMIC_RELAXED, __HIP_MEMORY_SCOPE_AGENT);
          u32 a3_ = __hip_atomic_load(&arrive[base + 3], __ATOMIC_RELAXED, __HIP_MEMORY_SCOPE_AGENT);
          if (__all(umin4(a0_, a1_, a2_, a3_) >= target)) break;
          __builtin_amdgcn_s_sleep(1);
        }
        if (tid == 0)
          __hip_atomic_store(flag, target, __ATOMIC_RELAXED, __HIP_MEMORY_SCOPE_AGENT);
      }
    }
    if (tid == 0) {
      while (__hip_atomic_load(flag, __ATOMIC_RELAXED, __HIP_MEMORY_SCOPE_AGENT) < target)
        __builtin_amdgcn_s_sleep(2);
    }
    C_FENCE();
    __syncthreads();
  }
}

// ---------------- key/val GEMM: key -> [b][t][k], val -> [b][t][w] ----------------
struct KVP {
  const float* enc2; const float* Wk; const float* bk; const float* Wv; const float* bv;
  float* key_bt; float* val;
};

__global__ __launch_bounds__(256) void k_keyval(KVP P) {
  __shared__ float As[16 * 132];
  __shared__ float Bs[16 * 132];
  const int tid = threadIdx.x, bid = blockIdx.x;
  const int mt = bid % 150, nt = bid / 150;
  const int m0 = mt * 128, n0 = nt * 128;
  const int tx = tid & 15, ty = tid >> 4;
  const int mmS = tid & 127;
  const int gmS = m0 + mmS;
  const int bS = gmS / 600, tS = gmS % 600;
  const int kkS0 = tid >> 7;
  const int nnS0 = tid >> 4;
  const int kkSB = tid & 15;
  float acc[8][8];
  #pragma unroll
  for (int i = 0; i < 8; i++)
    #pragma unroll
    for (int jj = 0; jj < 8; jj++) acc[i][jj] = 0.f;
  for (int k0 = 0; k0 < 1024; k0 += 16) {
    #pragma unroll
    for (int r = 0; r < 8; r++) {
      int kk = kkS0 + 2 * r;
      As[kk * 132 + mmS] = P.enc2[(size_t)bS * 614400 + (size_t)(k0 + kk) * 600 + tS];
    }
    #pragma unroll
    for (int r = 0; r < 8; r++) {
      int nn = nnS0 + 16 * r;
      int n = n0 + nn;
      const float* src = (n < 512) ? (P.Wk + (size_t)n * 1024) : (P.Wv + (size_t)(n - 512) * 1024);
      Bs[kkSB * 132 + nn] = src[k0 + kkSB];
    }
    __syncthreads();
    #pragma unroll
    for (int kk = 0; kk < 16; kk++) {
      float4 A0 = *(const float4*)&As[kk * 132 + ty * 8];
      float4 A1 = *(const float4*)&As[kk * 132 + ty * 8 + 4];
      float4 B0 = *(const float4*)&Bs[kk * 132 + tx * 8];
      float4 B1 = *(const float4*)&Bs[kk * 132 + tx * 8 + 4];
      float av[8] = {A0.x, A0.y, A0.z, A0.w, A1.x, A1.y, A1.z, A1.w};
      float bw[8] = {B0.x, B0.y, B0.z, B0.w, B1.x, B1.y, B1.z, B1.w};
      #pragma unroll
      for (int i = 0; i < 8; i++)
        #pragma unroll
        for (int jj = 0; jj < 8; jj++) acc[i][jj] += av[i] * bw[jj];
    }
    __syncthreads();
  }
  #pragma unroll
  for (int i = 0; i < 8; i++) {
    int gm = m0 + ty * 8 + i;
    int b = gm / 600, t = gm % 600;
    #pragma unroll
    for (int jj = 0; jj < 8; jj++) {
      int n = n0 + tx * 8 + jj;
      float bia = (n < 512) ? P.bk[n] : P.bv[n - 512];
      float v = tanhf(acc[i][jj] + bia);
      if (n < 512) P.key_bt[(size_t)b * 307200 + (size_t)t * 512 + n] = v;
      else         P.val   [(size_t)b * 614400 + (size_t)t * 1024 + (n - 512)] = v;
    }
  }
}

// ---------------- persistent cooperative decoder (256 blocks x 512) ----------------
struct DecP {
  const float* Wq; const float* bq;
  const float* Wih_d; const float* Whh_d; const float* b_d;
  const float* Wc; const float* bc; const float* E;
  const int* flen;
  const float* key_bt; const float* val;
  float* h_d; float* c_d; float* last; float* q; float* ctx;
  float* scores; float* stats;
  float* out;
  u32* bar;
};

__global__ __launch_bounds__(512) void k_decoder(DecP P) {
  __shared__ float sm[16384];   // 64 KiB, reused per phase
  const int tid = threadIdx.x, bid = blockIdx.x;
  u32 epoch = 0;

  auto gsync = [&]() {
    VM_FENCE();
    __syncthreads();
    epoch++;
    const u32 target = 1000u + epoch;
    if (tid == 0)
      __hip_atomic_store(&P.bar[bid], target, __ATOMIC_RELAXED, __HIP_MEMORY_SCOPE_AGENT);
    if (bid == (int)(epoch & 255u)) {
      if (tid < 64) {
        const int base = tid * 4;
        for (;;) {
          u32 a0 = __hip_atomic_load(&P.bar[base + 0], __ATOMIC_RELAXED, __HIP_MEMORY_SCOPE_AGENT);
          u32 a1 = __hip_atomic_load(&P.bar[base + 1], __ATOMIC_RELAXED, __HIP_MEMORY_SCOPE_AGENT);
          u32 a2 = __hip_atomic_load(&P.bar[base + 2], __ATOMIC_RELAXED, __HIP_MEMORY_SCOPE_AGENT);
          u32 a3 = __hip_atomic_load(&P.bar[base + 3], __ATOMIC_RELAXED, __HIP_MEMORY_SCOPE_AGENT);
          if (__all(umin4(a0, a1, a2, a3) >= target)) break;
          __builtin_amdgcn_s_sleep(1);
        }
        if (tid == 0)
          __hip_atomic_store(&P.bar[256], target, __ATOMIC_RELAXED, __HIP_MEMORY_SCOPE_AGENT);
      }
    }
    if (tid == 0) {
      while (__hip_atomic_load(&P.bar[256], __ATOMIC_RELAXED, __HIP_MEMORY_SCOPE_AGENT) < target)
        __builtin_amdgcn_s_sleep(2);
    }
    C_FENCE();
    __syncthreads();
  };

  // P1: gates + cell update. 512 thr: b_lo(8) x chunk(8) x j_lo(8)
  auto phase_gates = [&](int i) {
    const int p = i & 1;
    const int bq4 = bid >> 6;
    const int jblk = bid & 63;       // same low bits across bq4 -> same XCD weight dedupe
    const int b_lo = tid & 7;
    const int chunk = (tid >> 3) & 7;
    const int j_lo = tid >> 6;
    const int bG = bq4 * 8 + b_lo;
    const int j = jblk * 8 + j_lo;
    const float* hsrc = P.h_d + p * 16384;
    for (int idx = tid; idx < 8 * 2048; idx += 512) {
      int bb = idx >> 11, c = idx & 2047;
      int gb = bq4 * 8 + bb;
      float v;
      if (c < 512)       v = ld_sys(&P.last[gb * 512 + c]);
      else if (c < 1536) v = ld_sys(&P.ctx[gb * 1024 + (c - 512)]);
      else               v = ld_sys(&hsrc[gb * 512 + (c - 1536)]);
      sm[bb * 2048 + (c ^ (bb << 2))] = v;
    }
    __syncthreads();
    const float* wbp; int rs, ko, k0;
    if (chunk < 6) { wbp = P.Wih_d; rs = 1536; ko = chunk * 256; k0 = chunk * 256; }
    else           { wbp = P.Whh_d; rs = 512;  ko = (chunk - 6) * 256; k0 = 1536 + (chunk - 6) * 256; }
    const float* r0 = wbp + (size_t)(j       ) * rs + ko;
    const float* r1 = wbp + (size_t)(512  + j) * rs + ko;
    const float* r2 = wbp + (size_t)(1024 + j) * rs + ko;
    const float* r3 = wbp + (size_t)(1536 + j) * rs + ko;
    const float* xb = sm + b_lo * 2048 + k0;
    const int xo = b_lo << 2;
    float a0 = 0.f, a1 = 0.f, a2 = 0.f, a3 = 0.f;
    #pragma unroll 4
    for (int k = 0; k < 256; k += 4) {
      float4 w0 = *(const float4*)(r0 + k);
      float4 w1 = *(const float4*)(r1 + k);
      float4 w2 = *(const float4*)(r2 + k);
      float4 w3 = *(const float4*)(r3 + k);
      float4 x  = *(const float4*)(xb + (k ^ xo));
      a0 += w0.x * x.x + w0.y * x.y + w0.z * x.z + w0.w * x.w;
      a1 += w1.x * x.x + w1.y * x.y + w1.z * x.z + w1.w * x.w;
      a2 += w2.x * x.x + w2.y * x.y + w2.z * x.z + w2.w * x.w;
      a3 += w3.x * x.x + w3.y * x.y + w3.z * x.z + w3.w * x.w;
    }
    a0 += __shfl_xor(a0, 8); a0 += __shfl_xor(a0, 16); a0 += __shfl_xor(a0, 32);
    a1 += __shfl_xor(a1, 8); a1 += __shfl_xor(a1, 16); a1 += __shfl_xor(a1, 32);
    a2 += __shfl_xor(a2, 8); a2 += __shfl_xor(a2, 16); a2 += __shfl_xor(a2, 32);
    a3 += __shfl_xor(a3, 8); a3 += __shfl_xor(a3, 16); a3 += __shfl_xor(a3, 32);
    if (chunk == 0) {
      float gi = a0 + P.b_d[j];
      float gf = a1 + P.b_d[512 + j];
      float gg = a2 + P.b_d[1024 + j];
      float go = a3 + P.b_d[1536 + j];
      int ci = bG * 512 + j;
      float co = P.c_d[ci];                      // block-private
      float cn = sigf(gf) * co + sigf(gi) * tanhf(gg);
      float hn = sigf(go) * tanhf(cn);
      P.c_d[ci] = cn;
      st_sys(&P.h_d[(p ^ 1) * 16384 + ci], hn);
    }
  };

  // P2: logits_i (1 logit/thread) + q_{i+1} (every 8th thread, 1 elem)
  auto phase_logits_q = [&](int i) {
    const int pn = (i & 1) ^ 1;
    const float* hsrc = P.h_d + pn * 16384;
    for (int idx = tid; idx < 16384; idx += 512) {
      int bb = idx >> 9, k = idx & 511;
      sm[bb * 512 + (k ^ ((bb & 7) << 2))] = ld_sys(&hsrc[idx]);
    }
    __syncthreads();
    if (i >= 0) {
      int pidx = bid * 512 + tid;          // 0..131071 = 32 b x 4096 v
      int bb = pidx & 31;
      int v = pidx >> 5;
      const float* w0 = P.Wc + (size_t)v * 512;
      const float* hbp = sm + bb * 512;
      const int xo = (bb & 7) << 2;
      float s0 = 0.f;
      #pragma unroll 4
      for (int k = 0; k < 512; k += 4) {
        float4 A0 = *(const float4*)(w0 + k);
        int kx = k ^ xo;
        s0 += A0.x * hbp[kx] + A0.y * hbp[kx + 1] + A0.z * hbp[kx + 2] + A0.w * hbp[kx + 3];
      }
      st_sys(&P.out[(size_t)bb * 491520 + (size_t)i * 4096 + v], s0 + P.bc[v]);
    }
    if ((tid & 7) == 0) {
      int qp = bid * 64 + (tid >> 3);      // 0..16383 = 32 b x 512 d
      int bb = qp & 31;
      int d = qp >> 5;
      const float* w0 = P.Wq + (size_t)d * 512;
      const float* hbp = sm + bb * 512;
      const int xo = (bb & 7) << 2;
      float s0 = 0.f;
      #pragma unroll 4
      for (int k = 0; k < 512; k += 4) {
        float4 A0 = *(const float4*)(w0 + k);
        int kx = k ^ xo;
        s0 += A0.x * hbp[kx] + A0.y * hbp[kx + 1] + A0.z * hbp[kx + 2] + A0.w * hbp[kx + 3];
      }
      st_sys(&P.q[bb * 512 + d], tanhf(s0 + P.bq[d]));
    }
  };

  // P3: argmax_i (blocks 0..31) || scores_{i+1} chunks (blocks 32..223: 32 b x 6 chunks)
  auto phase_amax_scores = [&](int i, bool do_scores) {
    if (bid < 32) {
      if (i < 0) return;
      const float* row = P.out + (size_t)bid * 491520 + (size_t)i * 4096;
      float bv = -INFINITY; int bi = 0;
      for (int v = tid; v < 4096; v += 512) {
        float x = ld_sys(&row[v]);
        if (x > bv) { bv = x; bi = v; }
      }
      float* smax = sm;
      int* sidx = (int*)(sm + 512);
      smax[tid] = bv; sidx[tid] = bi;
      __syncthreads();
      for (int off = 256; off > 0; off >>= 1) {
        if (tid < off) {
          float ov = smax[tid + off]; int oi = sidx[tid + off];
          if (ov > smax[tid] || (ov == smax[tid] && oi < sidx[tid])) { smax[tid] = ov; sidx[tid] = oi; }
        }
        __syncthreads();
      }
      int widx = sidx[0];
      if (tid < 512 && tid < 512) {}
      for (int k = tid; k < 512; k += 512)
        st_sys(&P.last[bid * 512 + k], P.E[(size_t)widx * 512 + k]);
    } else if (bid < 224) {
      if (!do_scores) return;
      const int sb = bid - 32;
      const int b = sb / 6, ch = sb - 6 * b;
      const int t0 = ch * 100;
      const int wv = tid >> 6, lane = tid & 63;
      const int kbase = lane * 8;
      const int len = P.flen[b];
      float qreg[8];
      {
        const float* qb = P.q + b * 512 + kbase;
        #pragma unroll
        for (int jj = 0; jj < 8; jj++) qreg[jj] = ld_sys(&qb[jj]);
      }
      const float* kb = P.key_bt + (size_t)b * 307200 + kbase;
      float mloc = -INFINITY;
      for (int t = t0 + wv; t < t0 + 100; t += 8) {
        const float4* kr = (const float4*)(kb + (size_t)t * 512);
        float4 u0 = kr[0];
        float4 u1 = kr[1];
        float s = qreg[0] * u0.x + qreg[1] * u0.y + qreg[2] * u0.z + qreg[3] * u0.w
                + qreg[4] * u1.x + qreg[5] * u1.y + qreg[6] * u1.z + qreg[7] * u1.w;
        s += __shfl_xor(s, 1);  s += __shfl_xor(s, 2);  s += __shfl_xor(s, 4);
        s += __shfl_xor(s, 8);  s += __shfl_xor(s, 16); s += __shfl_xor(s, 32);
        float sc = (t < len) ? 2.0f * s : -1e30f;
        if (lane == 0) st_sys(&P.scores[b * 600 + t], sc);
        mloc = fmaxf(mloc, sc);
      }
      if (lane == 0) sm[wv] = mloc;
      __syncthreads();
      if (tid == 0) {
        float m = sm[0];
        #pragma unroll
        for (int w = 1; w < 8; w++) m = fmaxf(m, sm[w]);
        st_sys(&P.stats[b * 8 + ch], m);
      }
    }
  };

  // P4: ctx for step att_i + att_seq writes (32 b x 8 w-chunks)
  auto phase_ctx = [&](int att_i) {
    const int b = bid >> 3, wblk = bid & 7;
    const float* st = P.stats + b * 8;
    float M = fmaxf(fmaxf(fmaxf(ld_sys(&st[0]), ld_sys(&st[1])), fmaxf(ld_sys(&st[2]), ld_sys(&st[3]))),
                    fmaxf(ld_sys(&st[4]), ld_sys(&st[5])));
    float* pl = sm;              // [600]
    float* red = sm + 640;       // [512]
    float Lloc = 0.f;
    for (int t = tid; t < 600; t += 512) {
      float e = expf(ld_sys(&P.scores[b * 600 + t]) - M);
      pl[t] = e;
      Lloc += e;
    }
    red[tid] = Lloc;
    __syncthreads();
    for (int off = 256; off > 0; off >>= 1) {
      if (tid < off) red[tid] += red[tid + off];
      __syncthreads();
    }
    const float L = red[0];
    __syncthreads();
    const float invL = 1.0f / L;
    if (wblk == 0) {
      for (int t = tid; t < 600; t += 512)
        P.out[15728640ull + (size_t)b * 72000 + (size_t)att_i * 600 + t] = pl[t] * invL;
    }
    const int w = (wblk << 7) + (tid & 127);
    const int th = tid >> 7;                 // 0..3, t-quarters of 150
    const float* vb = P.val + (size_t)b * 614400 + w;
    float acc = 0.f;
    #pragma unroll 8
    for (int t = th * 150; t < th * 150 + 150; t++)
      acc += pl[t] * vb[(size_t)t * 1024];
    red[tid] = acc;
    __syncthreads();
    if (tid < 128)
      st_sys(&P.ctx[b * 1024 + (wblk << 7) + tid],
             (red[tid] + red[tid + 128] + red[tid + 256] + red[tid + 384]) * invL);
  };

  // ---- pipeline ----
  phase_logits_q(-1);            // q_0
  gsync();
  phase_amax_scores(-1, true);   // scores_0
  gsync();
  phase_ctx(0);                  // ctx_0, att_seq[:,0,:]
  gsync();
  for (int i = 0; i < 120; i++) {
    phase_gates(i);
    gsync();
    phase_logits_q(i);           // logits_i, q_{i+1}
    gsync();
    phase_amax_scores(i, i < 119);
    gsync();
    if (i < 119) phase_ctx(i + 1);
    gsync();
  }
}

// ---------------- launch ----------------
extern "C" void kernel_launch(void* const* d_in, const int* in_sizes, int n_in,
                              void* d_out, int out_size, void* d_ws, size_t ws_size,
                              hipStream_t stream) {
  const float* audio = (const float*)d_in[0];
  const float* Wih_f = (const float*)d_in[1];
  const float* Whh_f = (const float*)d_in[2];
  const float* b_f   = (const float*)d_in[3];
  const float* Wih_b = (const float*)d_in[4];
  const float* Whh_b = (const float*)d_in[5];
  const float* b_b   = (const float*)d_in[6];
  const float* Wq    = (const float*)d_in[7];
  const float* bq    = (const float*)d_in[8];
  const float* Wk    = (const float*)d_in[9];
  const float* bk    = (const float*)d_in[10];
  const float* Wv    = (const float*)d_in[11];
  const float* bv    = (const float*)d_in[12];
  const float* Wih_d = (const float*)d_in[13];
  const float* Whh_d = (const float*)d_in[14];
  const float* b_d   = (const float*)d_in[15];
  const float* Wc    = (const float*)d_in[16];
  const float* bc    = (const float*)d_in[17];
  const float* E     = (const float*)d_in[18];
  const int*   flen  = (const int*)d_in[19];
  float* out = (float*)d_out;
  char* ws = (char*)d_ws;

  u32*   bar     = (u32*)  (ws + OFF_BAR);
  float* h_enc   = (float*)(ws + OFF_HENC);
  float* c_enc   = (float*)(ws + OFF_CENC);
  float* h_d     = (float*)(ws + OFF_HD);
  float* c_d     = (float*)(ws + OFF_CD);
  float* last    = (float*)(ws + OFF_LAST);
  float* qbuf    = (float*)(ws + OFF_Q);
  float* ctx     = (float*)(ws + OFF_CTX);
  float* scores  = (float*)(ws + OFF_SCORES);
  float* stats   = (float*)(ws + OFF_STATS);
  float* audio_T = (float*)(ws + OFF_AUDIOT);
  float* enc2    = (float*)(ws + OFF_ENC2);
  float* key_bt  = (float*)(ws + OFF_KEYT);
  float* val     = (float*)(ws + OFF_VAL);

  (void)hipMemsetAsync(ws, 0, STATE_BYTES, stream);
  k_init_last<<<64, 256, 0, stream>>>(E, last);
  k_prep_audio<<<(T_ * FIN_ * 32 + 255) / 256, 256, 0, stream>>>(audio, audio_T);

  EncP ep{audio_T, Wih_f, Whh_f, b_f, Wih_b, Whh_b, b_b, h_enc, c_enc, enc2, bar};
  void* ea[] = { &ep };
  (void)hipLaunchCooperativeKernel((const void*)k_encoder, dim3(256), dim3(512), ea, 0, stream);

  KVP kp{enc2, Wk, bk, Wv, bv, key_bt, val};
  k_keyval<<<1800, 256, 0, stream>>>(kp);

  DecP dp{Wq, bq, Wih_d, Whh_d, b_d, Wc, bc, E, flen, key_bt, val,
          h_d, c_d, last, qbuf, ctx, scores, stats, out, bar};
  void* da[] = { &dp };
  (void)hipLaunchCooperativeKernel((const void*)k_decoder, dim3(256), dim3(512), da, 0, stream);
}

// Round 8
// 21052.565 us; speedup vs baseline: 3.5883x; 1.0424x over previous
//
#include <hip/hip_runtime.h>
#include <math.h>

typedef unsigned int u32;
typedef float nt_f4 __attribute__((ext_vector_type(4)));

#define T_    600
#define FIN_  120

// ---- ws byte offsets ----
#define OFF_BAR      0ull          // 2048 B: arrive[256]; enc flags 257..264; dec flags 272..275
#define OFF_HENC     2048ull       // [2 parity][2 dir][512][32]
#define OFF_CENC     264192ull     // (unused)
#define OFF_HD       395264ull     // [2 parity][32][512]
#define OFF_CD       526336ull     // [32][512]
#define STATE_BYTES  591872ull     // memset-0 region
#define OFF_LAST     591872ull     // [32][512]
#define OFF_Q        657408ull     // [32][512]
#define OFF_CTX      722944ull     // [32][1024]
#define OFF_SCORES   854016ull     // [32][600]
#define OFF_STATS    930816ull     // (legacy, unused)
#define OFF_AUDIOT   931840ull     // [600][120][32]
#define OFF_ENC2     10147840ull   // [32][1024][600]; decoder reuses: ctx_ch[32][6][1024], Mch[192], Sch[192]
#define OFF_KEYT     88791040ull   // key_bt [32][600][512]
#define OFF_VAL      128112640ull  // val [32][600][1024]

__device__ __forceinline__ float sigf(float x) { return 1.0f / (1.0f + expf(-x)); }
__device__ __forceinline__ u32 umin4(u32 a, u32 b, u32 c, u32 d) {
  u32 x = a < b ? a : b; u32 y = c < d ? c : d; return x < y ? x : y;
}
// L3-coherent scalar access — bypasses non-coherent L2.
__device__ __forceinline__ void st_sys(float* p, float v) {
  __hip_atomic_store(p, v, __ATOMIC_RELAXED, __HIP_MEMORY_SCOPE_AGENT);
}
__device__ __forceinline__ float ld_sys(const float* p) {
  return __hip_atomic_load(p, __ATOMIC_RELAXED, __HIP_MEMORY_SCOPE_AGENT);
}
#define VM_FENCE() asm volatile("s_waitcnt vmcnt(0)" ::: "memory")
#define C_FENCE()  asm volatile("" ::: "memory")

// ---------------- prep ----------------
__global__ __launch_bounds__(256) void k_prep_audio(const float* __restrict__ audio,
                                                    float* __restrict__ audio_T) {
  int idx = blockIdx.x * 256 + threadIdx.x;
  if (idx >= T_ * FIN_ * 32) return;
  int b = idx & 31;
  int r = idx >> 5;
  int f = r % FIN_;
  int t = r / FIN_;
  audio_T[idx] = audio[(size_t)b * (T_ * FIN_) + t * FIN_ + f];
}

__global__ __launch_bounds__(256) void k_init_last(const float* __restrict__ E,
                                                   float* __restrict__ last) {
  int idx = blockIdx.x * 256 + threadIdx.x;
  if (idx < 32 * 512) last[idx] = E[idx & 511];
}

// ---------------- persistent encoder: 8 groups (dir x bquad) x 32 blocks x 512 thr ----------------
struct EncP {
  const float* audio_T;
  const float* Wih_f; const float* Whh_f; const float* b_f;
  const float* Wih_b; const float* Whh_b; const float* b_b;
  float* h_enc; float* enc2;
  u32* bar;
};

__global__ __launch_bounds__(512) void k_encoder(EncP P) {
  __shared__ float hl[4160];          // staged h: [512 j][8 b] + kc-bank padding
  __shared__ float hsave[4096];       // [128 r][32 slot] write-combine
  const int tid = threadIdx.x, bid = blockIdx.x;
  const int grp = bid >> 5;           // 0..7 = dir*4 + bquad
  const int dir = grp >> 2, bquad = grp & 3;
  const int jblk = bid & 31;
  const int b_lo = tid & 7;
  const int kc = (tid >> 3) & 3;
  const int j_lo = tid >> 5;          // 0..15
  const int j = jblk * 16 + j_lo;
  const int bG = bquad * 8 + b_lo;
  const float* Wih  = dir ? P.Wih_b : P.Wih_f;
  const float* Whh  = dir ? P.Whh_b : P.Whh_f;
  const float* bias = dir ? P.b_b   : P.b_f;
  u32* arrive = P.bar + grp * 32;
  u32* flag   = P.bar + 257 + grp;

  const float* WihR0 = Wih + (size_t)(j       ) * 120 + kc * 30;
  const float* WihR1 = Wih + (size_t)(512  + j) * 120 + kc * 30;
  const float* WihR2 = Wih + (size_t)(1024 + j) * 120 + kc * 30;
  const float* WihR3 = Wih + (size_t)(1536 + j) * 120 + kc * 30;
  const float* WhhR0 = Whh + (size_t)(j       ) * 512 + kc * 128;
  const float* WhhR1 = Whh + (size_t)(512  + j) * 512 + kc * 128;
  const float* WhhR2 = Whh + (size_t)(1024 + j) * 512 + kc * 128;
  const float* WhhR3 = Whh + (size_t)(1536 + j) * 512 + kc * 128;
  const float bia0 = bias[j], bia1 = bias[512 + j], bia2 = bias[1024 + j], bia3 = bias[1536 + j];

  float creg = 0.f;                   // cell state for (bG, j), owned by kc==0 lanes

  for (int s = 0; s < 600; s++) {
    const int t = dir ? (599 - s) : s;
    const int p = s & 1;
    {
      const float* hsrc = P.h_enc + (size_t)(p * 2 + dir) * 16384 + bquad * 8;
      for (int idx = tid; idx < 4096; idx += 512) {
        int jj = idx >> 3, bb = idx & 7;
        hl[idx + ((idx >> 10) << 3)] = ld_sys(hsrc + jj * 32 + bb);
      }
    }
    __syncthreads();

    float a0 = 0.f, a1 = 0.f, a2 = 0.f, a3 = 0.f;
    // x part: 30 k per quarter
    {
      const float* xg = P.audio_T + (size_t)t * 3840 + (kc * 30) * 32 + bG;
      for (int kl = 0; kl < 30; kl += 2) {
        float2 w0 = *(const float2*)(WihR0 + kl);
        float2 w1 = *(const float2*)(WihR1 + kl);
        float2 w2 = *(const float2*)(WihR2 + kl);
        float2 w3 = *(const float2*)(WihR3 + kl);
        float x0 = xg[(kl + 0) * 32], x1 = xg[(kl + 1) * 32];
        a0 += w0.x * x0 + w0.y * x1;
        a1 += w1.x * x0 + w1.y * x1;
        a2 += w2.x * x0 + w2.y * x1;
        a3 += w3.x * x0 + w3.y * x1;
      }
    }
    // h part: 128 k per quarter
    {
      const float* hb = hl + kc * 1032 + b_lo;
      #pragma unroll 4
      for (int kl = 0; kl < 128; kl += 4) {
        float4 w0 = *(const float4*)(WhhR0 + kl);
        float4 w1 = *(const float4*)(WhhR1 + kl);
        float4 w2 = *(const float4*)(WhhR2 + kl);
        float4 w3 = *(const float4*)(WhhR3 + kl);
        float x0 = hb[(kl + 0) * 8], x1 = hb[(kl + 1) * 8];
        float x2 = hb[(kl + 2) * 8], x3 = hb[(kl + 3) * 8];
        a0 += w0.x * x0 + w0.y * x1 + w0.z * x2 + w0.w * x3;
        a1 += w1.x * x0 + w1.y * x1 + w1.z * x2 + w1.w * x3;
        a2 += w2.x * x0 + w2.y * x1 + w2.z * x2 + w2.w * x3;
        a3 += w3.x * x0 + w3.y * x1 + w3.z * x2 + w3.w * x3;
      }
    }
    a0 += __shfl_xor(a0, 8); a0 += __shfl_xor(a0, 16);
    a1 += __shfl_xor(a1, 8); a1 += __shfl_xor(a1, 16);
    a2 += __shfl_xor(a2, 8); a2 += __shfl_xor(a2, 16);
    a3 += __shfl_xor(a3, 8); a3 += __shfl_xor(a3, 16);
    if (kc == 0) {
      float gi = a0 + bia0, gf = a1 + bia1, gg = a2 + bia2, go = a3 + bia3;
      creg = sigf(gf) * creg + sigf(gi) * tanhf(gg);
      float hn = sigf(go) * tanhf(creg);
      st_sys(&P.h_enc[(size_t)((p ^ 1) * 2 + dir) * 16384 + j * 32 + bG], hn);
      int r = j_lo * 8 + b_lo;
      hsave[r * 32 + ((t + r) & 31)] = hn;
    }
    // ---- barrier + deferred enc2 flush ----
    VM_FENCE();
    __syncthreads();
    const u32 target = (u32)(s + 1);
    if (tid == 0)
      __hip_atomic_store(&arrive[jblk], target, __ATOMIC_RELAXED, __HIP_MEMORY_SCOPE_AGENT);
    {
      bool doflush; int tbase;
      if (dir == 0) { doflush = ((t & 31) == 31) || (t == 599); tbase = (t == 599) ? 576 : (t - 31); }
      else          { doflush = ((t & 31) == 0);                 tbase = t; }
      if (doflush) {
        const int fmaxv = 599 - tbase;
        for (int idx = tid; idx < 4096; idx += 512) {
          int r = idx >> 5, f = idx & 31;
          if (f <= fmaxv) {
            float v = hsave[r * 32 + ((tbase + f + r) & 31)];
            int jl = r >> 3, bl = r & 7;
            P.enc2[(size_t)(bquad * 8 + bl) * 614400 +
                   (size_t)(dir * 512 + jblk * 16 + jl) * 600 + tbase + f] = v;
          }
        }
      }
    }
    if (jblk == (s & 31)) {
      if (tid < 8) {
        const int base = tid * 4;
        for (;;) {
          u32 a0_ = __hip_atomic_load(&arrive[base + 0], __ATOMIC_RELAXED, __HIP_MEMORY_SCOPE_AGENT);
          u32 a1_ = __hip_atomic_load(&arrive[base + 1], __ATOMIC_RELAXED, __HIP_MEMORY_SCOPE_AGENT);
          u32 a2_ = __hip_atomic_load(&arrive[base + 2], __ATOMIC_RELAXED, __HIP_MEMORY_SCOPE_AGENT);
          u32 a3_ = __hip_atomic_load(&arrive[base + 3], __ATOMIC_RELAXED, __HIP_MEMORY_SCOPE_AGENT);
          if (__all(umin4(a0_, a1_, a2_, a3_) >= target)) break;
          __builtin_amdgcn_s_sleep(1);
        }
        if (tid == 0)
          __hip_atomic_store(flag, target, __ATOMIC_RELAXED, __HIP_MEMORY_SCOPE_AGENT);
      }
    }
    if (tid == 0) {
      while (__hip_atomic_load(flag, __ATOMIC_RELAXED, __HIP_MEMORY_SCOPE_AGENT) < target)
        __builtin_amdgcn_s_sleep(2);
    }
    C_FENCE();
    __syncthreads();
  }
}

// ---------------- key/val GEMM: key -> [b][t][k], val -> [b][t][w] ----------------
struct KVP {
  const float* enc2; const float* Wk; const float* bk; const float* Wv; const float* bv;
  float* key_bt; float* val;
};

__global__ __launch_bounds__(256) void k_keyval(KVP P) {
  __shared__ float As[16 * 132];
  __shared__ float Bs[16 * 132];
  const int tid = threadIdx.x, bid = blockIdx.x;
  const int mt = bid % 150, nt = bid / 150;
  const int m0 = mt * 128, n0 = nt * 128;
  const int tx = tid & 15, ty = tid >> 4;
  const int mmS = tid & 127;
  const int gmS = m0 + mmS;
  const int bS = gmS / 600, tS = gmS % 600;
  const int kkS0 = tid >> 7;
  const int nnS0 = tid >> 4;
  const int kkSB = tid & 15;
  float acc[8][8];
  #pragma unroll
  for (int i = 0; i < 8; i++)
    #pragma unroll
    for (int jj = 0; jj < 8; jj++) acc[i][jj] = 0.f;
  for (int k0 = 0; k0 < 1024; k0 += 16) {
    #pragma unroll
    for (int r = 0; r < 8; r++) {
      int kk = kkS0 + 2 * r;
      As[kk * 132 + mmS] = P.enc2[(size_t)bS * 614400 + (size_t)(k0 + kk) * 600 + tS];
    }
    #pragma unroll
    for (int r = 0; r < 8; r++) {
      int nn = nnS0 + 16 * r;
      int n = n0 + nn;
      const float* src = (n < 512) ? (P.Wk + (size_t)n * 1024) : (P.Wv + (size_t)(n - 512) * 1024);
      Bs[kkSB * 132 + nn] = src[k0 + kkSB];
    }
    __syncthreads();
    #pragma unroll
    for (int kk = 0; kk < 16; kk++) {
      float4 A0 = *(const float4*)&As[kk * 132 + ty * 8];
      float4 A1 = *(const float4*)&As[kk * 132 + ty * 8 + 4];
      float4 B0 = *(const float4*)&Bs[kk * 132 + tx * 8];
      float4 B1 = *(const float4*)&Bs[kk * 132 + tx * 8 + 4];
      float av[8] = {A0.x, A0.y, A0.z, A0.w, A1.x, A1.y, A1.z, A1.w};
      float bw[8] = {B0.x, B0.y, B0.z, B0.w, B1.x, B1.y, B1.z, B1.w};
      #pragma unroll
      for (int i = 0; i < 8; i++)
        #pragma unroll
        for (int jj = 0; jj < 8; jj++) acc[i][jj] += av[i] * bw[jj];
    }
    __syncthreads();
  }
  #pragma unroll
  for (int i = 0; i < 8; i++) {
    int gm = m0 + ty * 8 + i;
    int b = gm / 600, t = gm % 600;
    #pragma unroll
    for (int jj = 0; jj < 8; jj++) {
      int n = n0 + tx * 8 + jj;
      float bia = (n < 512) ? P.bk[n] : P.bv[n - 512];
      float v = tanhf(acc[i][jj] + bia);
      if (n < 512) P.key_bt[(size_t)b * 307200 + (size_t)t * 512 + n] = v;
      else         P.val   [(size_t)b * 614400 + (size_t)t * 1024 + (n - 512)] = v;
    }
  }
}

// ---------------- persistent decoder: 4 groups x 64 blocks x 512 thr (8 b per group) ----------------
struct DecP {
  const float* Wq; const float* bq;
  const float* Wih_d; const float* Whh_d; const float* b_d;
  const float* Wc; const float* bc; const float* E;
  const int* flen;
  const float* key_bt; const float* val;
  float* h_d; float* c_d; float* last; float* q; float* ctx;
  float* scores;
  float* ctx_ch; float* Mch; float* Sch;
  float* out;
  u32* bar;
};

__global__ __launch_bounds__(512) void k_decoder(DecP P) {
  __shared__ float sm[16384];
  const int tid = threadIdx.x, bid = blockIdx.x;
  const int g = bid >> 6;            // batch group: b in [g*8, g*8+8)
  const int jb = bid & 63;
  u32 epoch = 0;
  u32* arrive = P.bar + g * 64;
  u32* flag   = P.bar + 272 + g;

  auto gsync = [&]() {
    VM_FENCE();
    __syncthreads();
    epoch++;
    const u32 target = 1000u + epoch;
    if (tid == 0)
      __hip_atomic_store(&arrive[jb], target, __ATOMIC_RELAXED, __HIP_MEMORY_SCOPE_AGENT);
    if (jb == (int)(epoch & 63u)) {
      if (tid < 16) {
        const int base = tid * 4;
        for (;;) {
          u32 a0 = __hip_atomic_load(&arrive[base + 0], __ATOMIC_RELAXED, __HIP_MEMORY_SCOPE_AGENT);
          u32 a1 = __hip_atomic_load(&arrive[base + 1], __ATOMIC_RELAXED, __HIP_MEMORY_SCOPE_AGENT);
          u32 a2 = __hip_atomic_load(&arrive[base + 2], __ATOMIC_RELAXED, __HIP_MEMORY_SCOPE_AGENT);
          u32 a3 = __hip_atomic_load(&arrive[base + 3], __ATOMIC_RELAXED, __HIP_MEMORY_SCOPE_AGENT);
          if (__all(umin4(a0, a1, a2, a3) >= target)) break;
          __builtin_amdgcn_s_sleep(1);
        }
        if (tid == 0)
          __hip_atomic_store(flag, target, __ATOMIC_RELAXED, __HIP_MEMORY_SCOPE_AGENT);
      }
    }
    if (tid == 0) {
      while (__hip_atomic_load(flag, __ATOMIC_RELAXED, __HIP_MEMORY_SCOPE_AGENT) < target)
        __builtin_amdgcn_s_sleep(2);
    }
    C_FENCE();
    __syncthreads();
  };

  // P1: gates + cell update. 8 b x 2048 gates over 64 blocks.
  auto phase_gates = [&](int i) {
    const int p = i & 1;
    const int b_lo = tid & 7;
    const int chunk = (tid >> 3) & 7;
    const int j_lo = tid >> 6;
    const int bG = g * 8 + b_lo;
    const int j = jb * 8 + j_lo;
    const float* hsrc = P.h_d + p * 16384;
    for (int idx = tid; idx < 8 * 2048; idx += 512) {
      int bb = idx >> 11, c = idx & 2047;
      int gb = g * 8 + bb;
      float v;
      if (c < 512)       v = ld_sys(&P.last[gb * 512 + c]);
      else if (c < 1536) v = ld_sys(&P.ctx[gb * 1024 + (c - 512)]);
      else               v = ld_sys(&hsrc[gb * 512 + (c - 1536)]);
      sm[bb * 2048 + (c ^ (bb << 2))] = v;
    }
    __syncthreads();
    const float* wbp; int rs, ko, k0;
    if (chunk < 6) { wbp = P.Wih_d; rs = 1536; ko = chunk * 256; k0 = chunk * 256; }
    else           { wbp = P.Whh_d; rs = 512;  ko = (chunk - 6) * 256; k0 = 1536 + (chunk - 6) * 256; }
    const float* r0 = wbp + (size_t)(j       ) * rs + ko;
    const float* r1 = wbp + (size_t)(512  + j) * rs + ko;
    const float* r2 = wbp + (size_t)(1024 + j) * rs + ko;
    const float* r3 = wbp + (size_t)(1536 + j) * rs + ko;
    const float* xb = sm + b_lo * 2048 + k0;
    const int xo = b_lo << 2;
    float a0 = 0.f, a1 = 0.f, a2 = 0.f, a3 = 0.f;
    #pragma unroll 4
    for (int k = 0; k < 256; k += 4) {
      float4 w0 = *(const float4*)(r0 + k);
      float4 w1 = *(const float4*)(r1 + k);
      float4 w2 = *(const float4*)(r2 + k);
      float4 w3 = *(const float4*)(r3 + k);
      float4 x  = *(const float4*)(xb + (k ^ xo));
      a0 += w0.x * x.x + w0.y * x.y + w0.z * x.z + w0.w * x.w;
      a1 += w1.x * x.x + w1.y * x.y + w1.z * x.z + w1.w * x.w;
      a2 += w2.x * x.x + w2.y * x.y + w2.z * x.z + w2.w * x.w;
      a3 += w3.x * x.x + w3.y * x.y + w3.z * x.z + w3.w * x.w;
    }
    a0 += __shfl_xor(a0, 8); a0 += __shfl_xor(a0, 16); a0 += __shfl_xor(a0, 32);
    a1 += __shfl_xor(a1, 8); a1 += __shfl_xor(a1, 16); a1 += __shfl_xor(a1, 32);
    a2 += __shfl_xor(a2, 8); a2 += __shfl_xor(a2, 16); a2 += __shfl_xor(a2, 32);
    a3 += __shfl_xor(a3, 8); a3 += __shfl_xor(a3, 16); a3 += __shfl_xor(a3, 32);
    if (chunk == 0) {
      float gi = a0 + P.b_d[j];
      float gf = a1 + P.b_d[512 + j];
      float gg = a2 + P.b_d[1024 + j];
      float go = a3 + P.b_d[1536 + j];
      int ci = bG * 512 + j;
      float co = P.c_d[ci];
      float cn = sigf(gf) * co + sigf(gi) * tanhf(gg);
      float hn = sigf(go) * tanhf(cn);
      P.c_d[ci] = cn;
      st_sys(&P.h_d[(p ^ 1) * 16384 + ci], hn);
    }
  };

  // P2: logits_i (1/thread over 8 b x 4096 v) + q_{i+1} (every 8th thread)
  auto phase_logits_q = [&](int i) {
    const int pn = (i & 1) ^ 1;
    const float* hsrc = P.h_d + pn * 16384;
    for (int idx = tid; idx < 4096; idx += 512) {
      int bb = idx >> 9, k = idx & 511;
      sm[bb * 512 + (k ^ (bb << 2))] = ld_sys(&hsrc[(g * 8 + bb) * 512 + k]);
    }
    __syncthreads();
    if (i >= 0) {
      int pidx = jb * 512 + tid;         // 0..32767 = 8 b x 4096 v
      int bb = pidx & 7;
      int v = pidx >> 3;
      const float* w0 = P.Wc + (size_t)v * 512;
      const float* hbp = sm + bb * 512;
      const int xo = bb << 2;
      float s0 = 0.f;
      #pragma unroll 4
      for (int k = 0; k < 512; k += 4) {
        float4 A0 = *(const float4*)(w0 + k);
        int kx = k ^ xo;
        s0 += A0.x * hbp[kx] + A0.y * hbp[kx + 1] + A0.z * hbp[kx + 2] + A0.w * hbp[kx + 3];
      }
      st_sys(&P.out[(size_t)(g * 8 + bb) * 491520 + (size_t)i * 4096 + v], s0 + P.bc[v]);
    }
    if ((tid & 7) == 0) {
      int qp = jb * 64 + (tid >> 3);     // 0..4095 = 8 b x 512 d
      int bb = qp & 7;
      int d = qp >> 3;
      const float* w0 = P.Wq + (size_t)d * 512;
      const float* hbp = sm + bb * 512;
      const int xo = bb << 2;
      float s0 = 0.f;
      #pragma unroll 4
      for (int k = 0; k < 512; k += 4) {
        float4 A0 = *(const float4*)(w0 + k);
        int kx = k ^ xo;
        s0 += A0.x * hbp[kx] + A0.y * hbp[kx + 1] + A0.z * hbp[kx + 2] + A0.w * hbp[kx + 3];
      }
      st_sys(&P.q[(g * 8 + bb) * 512 + d], tanhf(s0 + P.bq[d]));
    }
  };

  // P3: argmax_i (jb 0..7) || scores_{i+1} + chunk-local softmax + val partial-dot (jb 8..55)
  auto phase_amax_scores = [&](int i, bool do_scores) {
    if (jb < 8) {
      if (i < 0) return;
      const int b = g * 8 + jb;
      const float* row = P.out + (size_t)b * 491520 + (size_t)i * 4096;
      float bv = -INFINITY; int bi = 0;
      for (int v = tid; v < 4096; v += 512) {
        float x = ld_sys(&row[v]);
        if (x > bv) { bv = x; bi = v; }
      }
      float* smax = sm;
      int* sidx = (int*)(sm + 512);
      smax[tid] = bv; sidx[tid] = bi;
      __syncthreads();
      for (int off = 256; off > 0; off >>= 1) {
        if (tid < off) {
          float ov = smax[tid + off]; int oi = sidx[tid + off];
          if (ov > smax[tid] || (ov == smax[tid] && oi < sidx[tid])) { smax[tid] = ov; sidx[tid] = oi; }
        }
        __syncthreads();
      }
      int widx = sidx[0];
      st_sys(&P.last[b * 512 + tid], P.E[(size_t)widx * 512 + tid]);
    } else if (jb < 56) {
      if (!do_scores) return;
      const int sb = jb - 8;
      const int bloc = sb / 6, ch = sb - 6 * bloc;
      const int b = g * 8 + bloc;
      const int t0 = ch * 100;
      float* pl   = sm;           // [100] scores
      float* wmax = sm + 104;     // [8]
      float* pl2  = sm + 112;     // [100] exp weights
      float* red  = sm + 256;     // [512]
      const int wv = tid >> 6, lane = tid & 63;
      const int kbase = lane * 8;
      const int len = P.flen[b];
      float qreg[8];
      {
        const float* qb = P.q + b * 512 + kbase;
        #pragma unroll
        for (int jj = 0; jj < 8; jj++) qreg[jj] = ld_sys(&qb[jj]);
      }
      const float* kb = P.key_bt + (size_t)b * 307200 + kbase;
      float mloc = -INFINITY;
      for (int t = t0 + wv; t < t0 + 100; t += 8) {
        const nt_f4* kr = (const nt_f4*)(kb + (size_t)t * 512);
        nt_f4 u0 = __builtin_nontemporal_load(kr);
        nt_f4 u1 = __builtin_nontemporal_load(kr + 1);
        float s = qreg[0] * u0.x + qreg[1] * u0.y + qreg[2] * u0.z + qreg[3] * u0.w
                + qreg[4] * u1.x + qreg[5] * u1.y + qreg[6] * u1.z + qreg[7] * u1.w;
        s += __shfl_xor(s, 1);  s += __shfl_xor(s, 2);  s += __shfl_xor(s, 4);
        s += __shfl_xor(s, 8);  s += __shfl_xor(s, 16); s += __shfl_xor(s, 32);
        float sc = (t < len) ? 2.0f * s : -1e30f;
        if (lane == 0) { st_sys(&P.scores[b * 600 + t], sc); pl[t - t0] = sc; }
        mloc = fmaxf(mloc, sc);
      }
      if (lane == 0) wmax[wv] = mloc;
      __syncthreads();
      float M = fmaxf(fmaxf(fmaxf(wmax[0], wmax[1]), fmaxf(wmax[2], wmax[3])),
                      fmaxf(fmaxf(wmax[4], wmax[5]), fmaxf(wmax[6], wmax[7])));
      float pv = (tid < 100) ? expf(pl[tid] - M) : 0.f;
      if (tid < 100) pl2[tid] = pv;
      red[tid] = pv;
      __syncthreads();
      for (int off = 256; off > 0; off >>= 1) {
        if (tid < off) red[tid] += red[tid + off];
        __syncthreads();
      }
      const float S = red[0];
      // val partial-dot: w = tid and tid+512
      const float* vb = P.val + (size_t)b * 614400 + (size_t)t0 * 1024 + tid;
      float acc0 = 0.f, acc1 = 0.f;
      #pragma unroll 4
      for (int tt = 0; tt < 100; tt++) {
        float p0 = pl2[tt];
        acc0 += p0 * __builtin_nontemporal_load(vb + (size_t)tt * 1024);
        acc1 += p0 * __builtin_nontemporal_load(vb + (size_t)tt * 1024 + 512);
      }
      float* cc = P.ctx_ch + (size_t)(b * 6 + ch) * 1024;
      st_sys(&cc[tid], acc0);
      st_sys(&cc[tid + 512], acc1);
      if (tid == 0) { st_sys(&P.Mch[b * 6 + ch], M); st_sys(&P.Sch[b * 6 + ch], S); }
    }
  };

  // P4: per-b recombine of 6 chunks -> ctx + att_seq writes (jb 0..7)
  auto phase_combine = [&](int att_i) {
    if (jb >= 8) return;
    const int b = g * 8 + jb;
    float Mc[6], Sc[6];
    #pragma unroll
    for (int c = 0; c < 6; c++) { Mc[c] = ld_sys(&P.Mch[b * 6 + c]); Sc[c] = ld_sys(&P.Sch[b * 6 + c]); }
    float M = Mc[0];
    #pragma unroll
    for (int c = 1; c < 6; c++) M = fmaxf(M, Mc[c]);
    float sca[6]; float L = 0.f;
    #pragma unroll
    for (int c = 0; c < 6; c++) { sca[c] = expf(Mc[c] - M); L += Sc[c] * sca[c]; }
    const float invL = 1.0f / L;
    for (int w = tid; w < 1024; w += 512) {
      float s = 0.f;
      #pragma unroll
      for (int c = 0; c < 6; c++)
        s += ld_sys(&P.ctx_ch[(size_t)(b * 6 + c) * 1024 + w]) * sca[c];
      st_sys(&P.ctx[b * 1024 + w], s * invL);
    }
    for (int t = tid; t < 600; t += 512) {
      float p = expf(ld_sys(&P.scores[b * 600 + t]) - M) * invL;
      P.out[15728640ull + (size_t)b * 72000 + (size_t)att_i * 600 + t] = p;
    }
  };

  // ---- pipeline (per-group independent) ----
  phase_logits_q(-1);            // q_0
  gsync();
  phase_amax_scores(-1, true);   // scores_0 + chunk ctx
  gsync();
  phase_combine(0);              // ctx_0, att_seq[:,0,:]
  gsync();
  for (int i = 0; i < 120; i++) {
    phase_gates(i);
    gsync();
    phase_logits_q(i);           // logits_i, q_{i+1}
    gsync();
    phase_amax_scores(i, i < 119);
    gsync();
    if (i < 119) phase_combine(i + 1);
    gsync();
  }
}

// ---------------- launch ----------------
extern "C" void kernel_launch(void* const* d_in, const int* in_sizes, int n_in,
                              void* d_out, int out_size, void* d_ws, size_t ws_size,
                              hipStream_t stream) {
  const float* audio = (const float*)d_in[0];
  const float* Wih_f = (const float*)d_in[1];
  const float* Whh_f = (const float*)d_in[2];
  const float* b_f   = (const float*)d_in[3];
  const float* Wih_b = (const float*)d_in[4];
  const float* Whh_b = (const float*)d_in[5];
  const float* b_b   = (const float*)d_in[6];
  const float* Wq    = (const float*)d_in[7];
  const float* bq    = (const float*)d_in[8];
  const float* Wk    = (const float*)d_in[9];
  const float* bk    = (const float*)d_in[10];
  const float* Wv    = (const float*)d_in[11];
  const float* bv    = (const float*)d_in[12];
  const float* Wih_d = (const float*)d_in[13];
  const float* Whh_d = (const float*)d_in[14];
  const float* b_d   = (const float*)d_in[15];
  const float* Wc    = (const float*)d_in[16];
  const float* bc    = (const float*)d_in[17];
  const float* E     = (const float*)d_in[18];
  const int*   flen  = (const int*)d_in[19];
  float* out = (float*)d_out;
  char* ws = (char*)d_ws;

  u32*   bar     = (u32*)  (ws + OFF_BAR);
  float* h_enc   = (float*)(ws + OFF_HENC);
  float* h_d     = (float*)(ws + OFF_HD);
  float* c_d     = (float*)(ws + OFF_CD);
  float* last    = (float*)(ws + OFF_LAST);
  float* qbuf    = (float*)(ws + OFF_Q);
  float* ctx     = (float*)(ws + OFF_CTX);
  float* scores  = (float*)(ws + OFF_SCORES);
  float* audio_T = (float*)(ws + OFF_AUDIOT);
  float* enc2    = (float*)(ws + OFF_ENC2);
  float* key_bt  = (float*)(ws + OFF_KEYT);
  float* val     = (float*)(ws + OFF_VAL);
  float* ctx_ch  = enc2;               // decoder reuses dead enc2 region
  float* Mch     = enc2 + 196608;      // 32*6*1024
  float* Sch     = Mch + 192;

  (void)hipMemsetAsync(ws, 0, STATE_BYTES, stream);
  k_init_last<<<64, 256, 0, stream>>>(E, last);
  k_prep_audio<<<(T_ * FIN_ * 32 + 255) / 256, 256, 0, stream>>>(audio, audio_T);

  EncP ep{audio_T, Wih_f, Whh_f, b_f, Wih_b, Whh_b, b_b, h_enc, enc2, bar};
  void* ea[] = { &ep };
  (void)hipLaunchCooperativeKernel((const void*)k_encoder, dim3(256), dim3(512), ea, 0, stream);

  KVP kp{enc2, Wk, bk, Wv, bv, key_bt, val};
  k_keyval<<<1800, 256, 0, stream>>>(kp);

  DecP dp{Wq, bq, Wih_d, Whh_d, b_d, Wc, bc, E, flen, key_bt, val,
          h_d, c_d, last, qbuf, ctx, scores, ctx_ch, Mch, Sch, out, bar};
  void* da[] = { &dp };
  (void)hipLaunchCooperativeKernel((const void*)k_decoder, dim3(256), dim3(512), da, 0, stream);
}